// Round 1
// baseline (1002.334 us; speedup 1.0000x reference)
//
#include <hip/hip_runtime.h>
#include <hip/hip_fp16.h>

#define NN 50000
#define NE 800000
#define D 128

typedef _Float16 half8_t __attribute__((ext_vector_type(8)));
typedef _Float16 half2_t __attribute__((ext_vector_type(2)));
typedef float f32x4 __attribute__((ext_vector_type(4)));

// ---------------- K0: init counters + summary slots ----------------
__global__ void k_init(int* cnt1, int* cnt2, int* fill1, int* fill2,
                       float* s1, float* s2) {
    int i = blockIdx.x * blockDim.x + threadIdx.x;
    int stride = gridDim.x * blockDim.x;
    for (int j = i; j < NN; j += stride) {
        cnt1[j] = 0; cnt2[j] = 0; fill1[j] = 0; fill2[j] = 0;
    }
    if (i < D) { s1[i] = 0.f; s2[i] = 0.f; }
}

// ---------------- K1: in-degree histogram (both graphs) ----------------
__global__ void k_count(const int* dst1, const int* dst2, int* cnt1, int* cnt2) {
    int i = blockIdx.x * blockDim.x + threadIdx.x;
    int stride = gridDim.x * blockDim.x;
    for (int e = i; e < NE; e += stride) {
        atomicAdd(&cnt1[dst1[e]], 1);
        atomicAdd(&cnt2[dst2[e]], 1);
    }
}

// ---------------- K2: exclusive scan -> row_ptr (one block per graph) ----------------
__global__ void k_scan(const int* cnt1, const int* cnt2, int* rp1, int* rp2) {
    const int* cnt = blockIdx.x ? cnt2 : cnt1;
    int* rp = blockIdx.x ? rp2 : rp1;
    __shared__ int part[1024];
    int t = threadIdx.x;
    const int CH = 49;  // 1024*49 = 50176 >= NN
    int base = t * CH;
    int local = 0;
    for (int k = 0; k < CH; k++) {
        int idx = base + k;
        if (idx < NN) local += cnt[idx];
    }
    part[t] = local;
    __syncthreads();
    for (int off = 1; off < 1024; off <<= 1) {
        int v = 0;
        if (t >= off) v = part[t - off];
        __syncthreads();
        part[t] += v;
        __syncthreads();
    }
    int run = part[t] - local;  // exclusive prefix
    for (int k = 0; k < CH; k++) {
        int idx = base + k;
        if (idx < NN) { rp[idx] = run; run += cnt[idx]; }
    }
    if (t == 1023) rp[NN] = part[1023];
}

// ---------------- K2b: dinv = rsqrt(deg), deg = in-degree + 1 (self loop) ----------------
__global__ void k_dinv(const int* cnt1, const int* cnt2, float* dinv1, float* dinv2) {
    int i = blockIdx.x * blockDim.x + threadIdx.x;
    int stride = gridDim.x * blockDim.x;
    for (int j = i; j < NN; j += stride) {
        dinv1[j] = rsqrtf((float)(cnt1[j] + 1));
        dinv2[j] = rsqrtf((float)(cnt2[j] + 1));
    }
}

// ---------------- K3: CSR fill ----------------
__global__ void k_fill(const int* src1, const int* dst1,
                       const int* src2, const int* dst2,
                       const int* rp1, const int* rp2,
                       int* fill1, int* fill2, int* col1, int* col2) {
    int i = blockIdx.x * blockDim.x + threadIdx.x;
    int stride = gridDim.x * blockDim.x;
    for (int e = i; e < NE; e += stride) {
        { int d = dst1[e]; int p = atomicAdd(&fill1[d], 1); col1[rp1[d] + p] = src1[e]; }
        { int d = dst2[e]; int p = atomicAdd(&fill2[d], 1); col2[rp2[d] + p] = src2[e]; }
    }
}

// ---------------- K4: 4 fused GEMMs (x*mask)@W -> f16, MFMA 16x16x32 f16 ----------------
// blockIdx.y: 0 = pos1, 1 = neg1 (rows gathered by perm1), 2 = pos2, 3 = neg2
__launch_bounds__(256)
__global__ void k_gemm(const float* __restrict__ x,
                       const float* __restrict__ W1, const float* __restrict__ W2,
                       const float* __restrict__ mp1, const float* __restrict__ mn1,
                       const float* __restrict__ mp2, const float* __restrict__ mn2,
                       const int* __restrict__ perm1, const int* __restrict__ perm2,
                       _Float16* xw_p1, _Float16* xw_n1,
                       _Float16* xw_p2, _Float16* xw_n2) {
    int which = blockIdx.y;
    const float* W = (which < 2) ? W1 : W2;
    const float* mask = (which == 0) ? mp1 : (which == 1) ? mn1 : (which == 2) ? mp2 : mn2;
    const int* perm = (which == 1) ? perm1 : (which == 3) ? perm2 : nullptr;
    _Float16* out = (which == 0) ? xw_p1 : (which == 1) ? xw_n1 : (which == 2) ? xw_p2 : xw_n2;

    // W transposed into LDS as f16: WT[n][k], padded row stride 136 halves (2-way bank alias only)
    __shared__ __align__(16) _Float16 WT[128][136];
    int t = threadIdx.x;
    for (int i = 0; i < 16; i++) {
        int idx = i * 256 + t;        // 4096 float4 over 128x128 W
        int k = idx >> 5;             // W row (K index)
        int j4 = (idx & 31) * 4;      // W col (N index)
        float4 w = ((const float4*)W)[idx];
        WT[j4 + 0][k] = (_Float16)w.x;
        WT[j4 + 1][k] = (_Float16)w.y;
        WT[j4 + 2][k] = (_Float16)w.z;
        WT[j4 + 3][k] = (_Float16)w.w;
    }
    __syncthreads();

    int wave = t >> 6;
    int lane = t & 63;
    int quad = lane >> 4;
    int m = lane & 15;
    int tile = blockIdx.x * 4 + wave;  // 16-row output tile
    if (tile * 16 >= NN) return;       // 50000 = 3125 * 16, tiles never partial

    int row = tile * 16 + m;
    int grow = perm ? perm[row] : row;
    const float* xrow = x + (long)grow * D;
    const float* mrow = mask + (long)grow * D;

    // A fragments: A[m=lane&15][k = quad*8 + j], 4 k-chunks of 32
    half8_t a[4];
    for (int kk = 0; kk < 4; kk++) {
        int k0 = kk * 32 + quad * 8;
        float4 xa = *(const float4*)(xrow + k0);
        float4 xb = *(const float4*)(xrow + k0 + 4);
        float4 ma = *(const float4*)(mrow + k0);
        float4 mb = *(const float4*)(mrow + k0 + 4);
        a[kk][0] = (_Float16)(xa.x * ma.x);
        a[kk][1] = (_Float16)(xa.y * ma.y);
        a[kk][2] = (_Float16)(xa.z * ma.z);
        a[kk][3] = (_Float16)(xa.w * ma.w);
        a[kk][4] = (_Float16)(xb.x * mb.x);
        a[kk][5] = (_Float16)(xb.y * mb.y);
        a[kk][6] = (_Float16)(xb.z * mb.z);
        a[kk][7] = (_Float16)(xb.w * mb.w);
    }

    for (int nt = 0; nt < 8; nt++) {
        f32x4 acc = {0.f, 0.f, 0.f, 0.f};
        for (int kk = 0; kk < 4; kk++) {
            half8_t b = *(const half8_t*)(&WT[nt * 16 + m][kk * 32 + quad * 8]);
            acc = __builtin_amdgcn_mfma_f32_16x16x32_f16(a[kk], b, acc, 0, 0, 0);
        }
        // C/D: col = lane&15 (N), row = quad*4 + reg (M)
        int n = nt * 16 + m;
        for (int r = 0; r < 4; r++) {
            int orow = tile * 16 + quad * 4 + r;
            out[(long)orow * D + n] = (_Float16)acc[r];
        }
    }
}

// ---------------- K5: CSR gather aggregation + bias + ReLU + summary ----------------
// wave per dst node; lane handles 2 dims. blockIdx.y selects graph.
__launch_bounds__(256)
__global__ void k_agg(const _Float16* __restrict__ xw_p1, const _Float16* __restrict__ xw_n1,
                      const _Float16* __restrict__ xw_p2, const _Float16* __restrict__ xw_n2,
                      const int* __restrict__ rp1, const int* __restrict__ col1,
                      const float* __restrict__ dinv1,
                      const int* __restrict__ rp2, const int* __restrict__ col2,
                      const float* __restrict__ dinv2,
                      const float* __restrict__ b1, const float* __restrict__ b2,
                      float* out) {
    int g = blockIdx.y;
    const _Float16* xwp = g ? xw_p2 : xw_p1;
    const _Float16* xwn = g ? xw_n2 : xw_n1;
    const int* rp = g ? rp2 : rp1;
    const int* col = g ? col2 : col1;
    const float* dinv = g ? dinv2 : dinv1;
    const float* bias = g ? b2 : b1;
    float* pos_out = out + (g ? 12800128L : 0L);
    float* neg_out = out + (g ? 19200128L : 6400000L);
    float* sum_out = out + (g ? 25600128L : 12800000L);

    __shared__ float ssum[128];
    int t = threadIdx.x;
    if (t < 128) ssum[t] = 0.f;
    __syncthreads();

    int wave = t >> 6, lane = t & 63;
    int i = blockIdx.x * 4 + wave;
    int j = lane * 2;
    if (i < NN) {
        float di = dinv[i];
        // self-loop term (gets second factor of di at the end)
        half2_t sp = *(const half2_t*)(xwp + (long)i * D + j);
        half2_t sn = *(const half2_t*)(xwn + (long)i * D + j);
        float apx = di * (float)sp[0], apy = di * (float)sp[1];
        float anx = di * (float)sn[0], any_ = di * (float)sn[1];
        int e0 = rp[i], e1 = rp[i + 1];
        for (int e = e0; e < e1; e++) {
            int s = col[e];
            float ds = dinv[s];
            half2_t vp = *(const half2_t*)(xwp + (long)s * D + j);
            half2_t vn = *(const half2_t*)(xwn + (long)s * D + j);
            apx += ds * (float)vp[0]; apy += ds * (float)vp[1];
            anx += ds * (float)vn[0]; any_ += ds * (float)vn[1];
        }
        float bx = bias[j], by = bias[j + 1];
        float px = fmaxf(0.f, di * apx + bx), py = fmaxf(0.f, di * apy + by);
        float nx = fmaxf(0.f, di * anx + bx), ny = fmaxf(0.f, di * any_ + by);
        float2 pv; pv.x = px; pv.y = py;
        float2 nv; nv.x = nx; nv.y = ny;
        *(float2*)(pos_out + (long)i * D + j) = pv;
        *(float2*)(neg_out + (long)i * D + j) = nv;
        atomicAdd(&ssum[j], px);
        atomicAdd(&ssum[j + 1], py);
    }
    __syncthreads();
    if (t < 128) atomicAdd(&sum_out[t], ssum[t] * (1.0f / NN));
}

extern "C" void kernel_launch(void* const* d_in, const int* in_sizes, int n_in,
                              void* d_out, int out_size, void* d_ws, size_t ws_size,
                              hipStream_t stream) {
    const float* x   = (const float*)d_in[0];
    const float* W1  = (const float*)d_in[1];
    const float* b1  = (const float*)d_in[2];
    const float* W2  = (const float*)d_in[3];
    const float* b2  = (const float*)d_in[4];
    const float* mp1 = (const float*)d_in[5];
    const float* mn1 = (const float*)d_in[6];
    const float* mp2 = (const float*)d_in[7];
    const float* mn2 = (const float*)d_in[8];
    const int* e1 = (const int*)d_in[9];
    const int* e2 = (const int*)d_in[10];
    const int* perm1 = (const int*)d_in[11];
    const int* perm2 = (const int*)d_in[12];
    const int* src1 = e1;       const int* dst1 = e1 + NE;
    const int* src2 = e2;       const int* dst2 = e2 + NE;
    float* out = (float*)d_out;

    // workspace carve
    char* w = (char*)d_ws;
    _Float16* xw_p1 = (_Float16*)w; w += (size_t)NN * D * 2;
    _Float16* xw_n1 = (_Float16*)w; w += (size_t)NN * D * 2;
    _Float16* xw_p2 = (_Float16*)w; w += (size_t)NN * D * 2;
    _Float16* xw_n2 = (_Float16*)w; w += (size_t)NN * D * 2;
    int* cnt1 = (int*)w;  w += (size_t)NN * 4;
    int* cnt2 = (int*)w;  w += (size_t)NN * 4;
    int* fill1 = (int*)w; w += (size_t)NN * 4;
    int* fill2 = (int*)w; w += (size_t)NN * 4;
    int* rp1 = (int*)w;   w += (size_t)(NN + 4) * 4;
    int* rp2 = (int*)w;   w += (size_t)(NN + 4) * 4;
    int* col1 = (int*)w;  w += (size_t)NE * 4;
    int* col2 = (int*)w;  w += (size_t)NE * 4;
    float* dinv1 = (float*)w; w += (size_t)NN * 4;
    float* dinv2 = (float*)w; w += (size_t)NN * 4;

    float* s1 = out + 12800000L;
    float* s2 = out + 25600128L;

    k_init<<<dim3(256), 256, 0, stream>>>(cnt1, cnt2, fill1, fill2, s1, s2);
    k_count<<<dim3(1024), 256, 0, stream>>>(dst1, dst2, cnt1, cnt2);
    k_scan<<<dim3(2), 1024, 0, stream>>>(cnt1, cnt2, rp1, rp2);
    k_dinv<<<dim3(196), 256, 0, stream>>>(cnt1, cnt2, dinv1, dinv2);
    k_fill<<<dim3(1024), 256, 0, stream>>>(src1, dst1, src2, dst2, rp1, rp2,
                                           fill1, fill2, col1, col2);
    k_gemm<<<dim3(782, 4), 256, 0, stream>>>(x, W1, W2, mp1, mn1, mp2, mn2,
                                             perm1, perm2, xw_p1, xw_n1, xw_p2, xw_n2);
    k_agg<<<dim3(12500, 2), 256, 0, stream>>>(xw_p1, xw_n1, xw_p2, xw_n2,
                                              rp1, col1, dinv1, rp2, col2, dinv2,
                                              b1, b2, out);
}

// Round 2
// 943.281 us; speedup vs baseline: 1.0626x; 1.0626x over previous
//
#include <hip/hip_runtime.h>
#include <hip/hip_fp16.h>

#define NN 50000
#define NE 800000
#define D 128

typedef _Float16 half8_t __attribute__((ext_vector_type(8)));
typedef _Float16 half4_t __attribute__((ext_vector_type(4)));
typedef float f32x4 __attribute__((ext_vector_type(4)));

// ---------------- K0: init counters + summary slots ----------------
__global__ void k_init(int* cnt1, int* cnt2, int* fill1, int* fill2,
                       float* s1, float* s2) {
    int i = blockIdx.x * blockDim.x + threadIdx.x;
    int stride = gridDim.x * blockDim.x;
    for (int j = i; j < NN; j += stride) {
        cnt1[j] = 0; cnt2[j] = 0; fill1[j] = 0; fill2[j] = 0;
    }
    if (i < D) { s1[i] = 0.f; s2[i] = 0.f; }
}

// ---------------- K1: in-degree histogram (both graphs) ----------------
__global__ void k_count(const int* dst1, const int* dst2, int* cnt1, int* cnt2) {
    int i = blockIdx.x * blockDim.x + threadIdx.x;
    int stride = gridDim.x * blockDim.x;
    for (int e = i; e < NE; e += stride) {
        atomicAdd(&cnt1[dst1[e]], 1);
        atomicAdd(&cnt2[dst2[e]], 1);
    }
}

// ---------------- K2: exclusive scan -> row_ptr (one block per graph) ----------------
__global__ void k_scan(const int* cnt1, const int* cnt2, int* rp1, int* rp2) {
    const int* cnt = blockIdx.x ? cnt2 : cnt1;
    int* rp = blockIdx.x ? rp2 : rp1;
    __shared__ int part[1024];
    int t = threadIdx.x;
    const int CH = 49;  // 1024*49 = 50176 >= NN
    int base = t * CH;
    int local = 0;
    for (int k = 0; k < CH; k++) {
        int idx = base + k;
        if (idx < NN) local += cnt[idx];
    }
    part[t] = local;
    __syncthreads();
    for (int off = 1; off < 1024; off <<= 1) {
        int v = 0;
        if (t >= off) v = part[t - off];
        __syncthreads();
        part[t] += v;
        __syncthreads();
    }
    int run = part[t] - local;  // exclusive prefix
    for (int k = 0; k < CH; k++) {
        int idx = base + k;
        if (idx < NN) { rp[idx] = run; run += cnt[idx]; }
    }
    if (t == 1023) rp[NN] = part[1023];
}

// ---------------- K2b: dinv = rsqrt(deg), deg = in-degree + 1 (self loop) ----------------
__global__ void k_dinv(const int* cnt1, const int* cnt2, float* dinv1, float* dinv2) {
    int i = blockIdx.x * blockDim.x + threadIdx.x;
    int stride = gridDim.x * blockDim.x;
    for (int j = i; j < NN; j += stride) {
        dinv1[j] = rsqrtf((float)(cnt1[j] + 1));
        dinv2[j] = rsqrtf((float)(cnt2[j] + 1));
    }
}

// ---------------- K3: CSR fill ----------------
__global__ void k_fill(const int* src1, const int* dst1,
                       const int* src2, const int* dst2,
                       const int* rp1, const int* rp2,
                       int* fill1, int* fill2, int* col1, int* col2) {
    int i = blockIdx.x * blockDim.x + threadIdx.x;
    int stride = gridDim.x * blockDim.x;
    for (int e = i; e < NE; e += stride) {
        { int d = dst1[e]; int p = atomicAdd(&fill1[d], 1); col1[rp1[d] + p] = src1[e]; }
        { int d = dst2[e]; int p = atomicAdd(&fill2[d], 1); col2[rp2[d] + p] = src2[e]; }
    }
}

// ---------------- K4: 4 fused GEMMs (x*mask)@W -> dinv-prescaled f16, interleaved ----------------
// blockIdx.y: 0 = pos1, 1 = neg1 (rows gathered by perm1), 2 = pos2, 3 = neg2
// Output row layout: xwi[i][0:128] = pos (which even), xwi[i][128:256] = neg (which odd),
// each element pre-scaled by dinv[i] (the src-side normalization factor).
__launch_bounds__(256)
__global__ void k_gemm(const float* __restrict__ x,
                       const float* __restrict__ W1, const float* __restrict__ W2,
                       const float* __restrict__ mp1, const float* __restrict__ mn1,
                       const float* __restrict__ mp2, const float* __restrict__ mn2,
                       const int* __restrict__ perm1, const int* __restrict__ perm2,
                       const float* __restrict__ dinv1, const float* __restrict__ dinv2,
                       _Float16* xwi1, _Float16* xwi2) {
    int which = blockIdx.y;
    const float* W = (which < 2) ? W1 : W2;
    const float* mask = (which == 0) ? mp1 : (which == 1) ? mn1 : (which == 2) ? mp2 : mn2;
    const int* perm = (which == 1) ? perm1 : (which == 3) ? perm2 : nullptr;
    const float* dinv = (which < 2) ? dinv1 : dinv2;
    _Float16* out = ((which < 2) ? xwi1 : xwi2) + ((which & 1) ? 128 : 0);

    // W transposed into LDS as f16: WT[n][k], padded row stride 136 halves
    __shared__ __align__(16) _Float16 WT[128][136];
    int t = threadIdx.x;
    for (int i = 0; i < 16; i++) {
        int idx = i * 256 + t;        // 4096 float4 over 128x128 W
        int k = idx >> 5;             // W row (K index)
        int j4 = (idx & 31) * 4;      // W col (N index)
        float4 w = ((const float4*)W)[idx];
        WT[j4 + 0][k] = (_Float16)w.x;
        WT[j4 + 1][k] = (_Float16)w.y;
        WT[j4 + 2][k] = (_Float16)w.z;
        WT[j4 + 3][k] = (_Float16)w.w;
    }
    __syncthreads();

    int wave = t >> 6;
    int lane = t & 63;
    int quad = lane >> 4;
    int m = lane & 15;
    int tile = blockIdx.x * 4 + wave;  // 16-row output tile
    if (tile * 16 >= NN) return;       // 50000 = 3125 * 16, tiles never partial

    int row = tile * 16 + m;
    int grow = perm ? perm[row] : row;
    const float* xrow = x + (long)grow * D;
    const float* mrow = mask + (long)grow * D;

    // A fragments: A[m=lane&15][k = quad*8 + j], 4 k-chunks of 32
    half8_t a[4];
    for (int kk = 0; kk < 4; kk++) {
        int k0 = kk * 32 + quad * 8;
        float4 xa = *(const float4*)(xrow + k0);
        float4 xb = *(const float4*)(xrow + k0 + 4);
        float4 ma = *(const float4*)(mrow + k0);
        float4 mb = *(const float4*)(mrow + k0 + 4);
        a[kk][0] = (_Float16)(xa.x * ma.x);
        a[kk][1] = (_Float16)(xa.y * ma.y);
        a[kk][2] = (_Float16)(xa.z * ma.z);
        a[kk][3] = (_Float16)(xa.w * ma.w);
        a[kk][4] = (_Float16)(xb.x * mb.x);
        a[kk][5] = (_Float16)(xb.y * mb.y);
        a[kk][6] = (_Float16)(xb.z * mb.z);
        a[kk][7] = (_Float16)(xb.w * mb.w);
    }

    // dinv for the 4 output rows this quad produces
    int rbase = tile * 16 + quad * 4;
    float ds0 = dinv[rbase + 0], ds1 = dinv[rbase + 1];
    float ds2 = dinv[rbase + 2], ds3 = dinv[rbase + 3];

    for (int nt = 0; nt < 8; nt++) {
        f32x4 acc = {0.f, 0.f, 0.f, 0.f};
        for (int kk = 0; kk < 4; kk++) {
            half8_t b = *(const half8_t*)(&WT[nt * 16 + m][kk * 32 + quad * 8]);
            acc = __builtin_amdgcn_mfma_f32_16x16x32_f16(a[kk], b, acc, 0, 0, 0);
        }
        // C/D: col = lane&15 (N), row = quad*4 + reg (M)
        int n = nt * 16 + m;
        out[(long)(rbase + 0) * 256 + n] = (_Float16)(acc[0] * ds0);
        out[(long)(rbase + 1) * 256 + n] = (_Float16)(acc[1] * ds1);
        out[(long)(rbase + 2) * 256 + n] = (_Float16)(acc[2] * ds2);
        out[(long)(rbase + 3) * 256 + n] = (_Float16)(acc[3] * ds3);
    }
}

// ---------------- K5: CSR gather aggregation + bias + ReLU + summary ----------------
// wave per dst node; lane handles 4 halves of the 256-half interleaved row.
// Lanes 0-31 -> pos dims 0..127, lanes 32-63 -> neg dims 0..127.
__launch_bounds__(256)
__global__ void k_agg(const _Float16* __restrict__ xwi1, const _Float16* __restrict__ xwi2,
                      const int* __restrict__ rp1, const int* __restrict__ col1,
                      const float* __restrict__ dinv1,
                      const int* __restrict__ rp2, const int* __restrict__ col2,
                      const float* __restrict__ dinv2,
                      const float* __restrict__ b1, const float* __restrict__ b2,
                      float* out) {
    int g = blockIdx.y;
    const _Float16* xwi = g ? xwi2 : xwi1;
    const int* rp = g ? rp2 : rp1;
    const int* col = g ? col2 : col1;
    const float* dinv = g ? dinv2 : dinv1;
    const float* bias = g ? b2 : b1;
    float* pos_out = out + (g ? 12800128L : 0L);
    float* neg_out = out + (g ? 19200128L : 6400000L);
    float* sum_out = out + (g ? 25600128L : 12800000L);

    __shared__ float ssum[128];
    int t = threadIdx.x;
    if (t < 128) ssum[t] = 0.f;
    __syncthreads();

    int wave = t >> 6, lane = t & 63;
    int i = blockIdx.x * 4 + wave;
    int j4 = lane * 4;  // half-index within the 256-half interleaved row
    if (i < NN) {
        // self-loop term (xwi already scaled by dinv[src])
        half4_t sv = *(const half4_t*)(xwi + (long)i * 256 + j4);
        float a0 = (float)sv[0], a1 = (float)sv[1], a2 = (float)sv[2], a3 = (float)sv[3];
        int e0 = rp[i], e1 = rp[i + 1];
        int e = e0;
        for (; e + 8 <= e1; e += 8) {
            int s0 = col[e + 0], s1 = col[e + 1], s2 = col[e + 2], s3 = col[e + 3];
            int s4 = col[e + 4], s5 = col[e + 5], s6 = col[e + 6], s7 = col[e + 7];
            half4_t v0 = *(const half4_t*)(xwi + (long)s0 * 256 + j4);
            half4_t v1 = *(const half4_t*)(xwi + (long)s1 * 256 + j4);
            half4_t v2 = *(const half4_t*)(xwi + (long)s2 * 256 + j4);
            half4_t v3 = *(const half4_t*)(xwi + (long)s3 * 256 + j4);
            half4_t v4 = *(const half4_t*)(xwi + (long)s4 * 256 + j4);
            half4_t v5 = *(const half4_t*)(xwi + (long)s5 * 256 + j4);
            half4_t v6 = *(const half4_t*)(xwi + (long)s6 * 256 + j4);
            half4_t v7 = *(const half4_t*)(xwi + (long)s7 * 256 + j4);
            a0 += (float)v0[0] + (float)v1[0] + (float)v2[0] + (float)v3[0]
                + (float)v4[0] + (float)v5[0] + (float)v6[0] + (float)v7[0];
            a1 += (float)v0[1] + (float)v1[1] + (float)v2[1] + (float)v3[1]
                + (float)v4[1] + (float)v5[1] + (float)v6[1] + (float)v7[1];
            a2 += (float)v0[2] + (float)v1[2] + (float)v2[2] + (float)v3[2]
                + (float)v4[2] + (float)v5[2] + (float)v6[2] + (float)v7[2];
            a3 += (float)v0[3] + (float)v1[3] + (float)v2[3] + (float)v3[3]
                + (float)v4[3] + (float)v5[3] + (float)v6[3] + (float)v7[3];
        }
        for (; e + 4 <= e1; e += 4) {
            int s0 = col[e + 0], s1 = col[e + 1], s2 = col[e + 2], s3 = col[e + 3];
            half4_t v0 = *(const half4_t*)(xwi + (long)s0 * 256 + j4);
            half4_t v1 = *(const half4_t*)(xwi + (long)s1 * 256 + j4);
            half4_t v2 = *(const half4_t*)(xwi + (long)s2 * 256 + j4);
            half4_t v3 = *(const half4_t*)(xwi + (long)s3 * 256 + j4);
            a0 += (float)v0[0] + (float)v1[0] + (float)v2[0] + (float)v3[0];
            a1 += (float)v0[1] + (float)v1[1] + (float)v2[1] + (float)v3[1];
            a2 += (float)v0[2] + (float)v1[2] + (float)v2[2] + (float)v3[2];
            a3 += (float)v0[3] + (float)v1[3] + (float)v2[3] + (float)v3[3];
        }
        for (; e < e1; e++) {
            int s = col[e];
            half4_t v = *(const half4_t*)(xwi + (long)s * 256 + j4);
            a0 += (float)v[0]; a1 += (float)v[1]; a2 += (float)v[2]; a3 += (float)v[3];
        }
        float di = dinv[i];
        int jj = (lane < 32) ? j4 : (j4 - 128);  // dim index within D
        float4 bv = *(const float4*)(bias + jj);
        float r0 = fmaxf(0.f, di * a0 + bv.x);
        float r1 = fmaxf(0.f, di * a1 + bv.y);
        float r2 = fmaxf(0.f, di * a2 + bv.z);
        float r3 = fmaxf(0.f, di * a3 + bv.w);
        float* dst = ((lane < 32) ? pos_out : neg_out) + (long)i * D + jj;
        float4 o; o.x = r0; o.y = r1; o.z = r2; o.w = r3;
        *(float4*)dst = o;
        if (lane < 32) {
            atomicAdd(&ssum[jj + 0], r0);
            atomicAdd(&ssum[jj + 1], r1);
            atomicAdd(&ssum[jj + 2], r2);
            atomicAdd(&ssum[jj + 3], r3);
        }
    }
    __syncthreads();
    if (t < 128) atomicAdd(&sum_out[t], ssum[t] * (1.0f / NN));
}

extern "C" void kernel_launch(void* const* d_in, const int* in_sizes, int n_in,
                              void* d_out, int out_size, void* d_ws, size_t ws_size,
                              hipStream_t stream) {
    const float* x   = (const float*)d_in[0];
    const float* W1  = (const float*)d_in[1];
    const float* b1  = (const float*)d_in[2];
    const float* W2  = (const float*)d_in[3];
    const float* b2  = (const float*)d_in[4];
    const float* mp1 = (const float*)d_in[5];
    const float* mn1 = (const float*)d_in[6];
    const float* mp2 = (const float*)d_in[7];
    const float* mn2 = (const float*)d_in[8];
    const int* e1 = (const int*)d_in[9];
    const int* e2 = (const int*)d_in[10];
    const int* perm1 = (const int*)d_in[11];
    const int* perm2 = (const int*)d_in[12];
    const int* src1 = e1;       const int* dst1 = e1 + NE;
    const int* src2 = e2;       const int* dst2 = e2 + NE;
    float* out = (float*)d_out;

    // workspace carve
    char* w = (char*)d_ws;
    _Float16* xwi1 = (_Float16*)w; w += (size_t)NN * 256 * 2;  // 25.6 MB interleaved
    _Float16* xwi2 = (_Float16*)w; w += (size_t)NN * 256 * 2;
    int* cnt1 = (int*)w;  w += (size_t)NN * 4;
    int* cnt2 = (int*)w;  w += (size_t)NN * 4;
    int* fill1 = (int*)w; w += (size_t)NN * 4;
    int* fill2 = (int*)w; w += (size_t)NN * 4;
    int* rp1 = (int*)w;   w += (size_t)(NN + 4) * 4;
    int* rp2 = (int*)w;   w += (size_t)(NN + 4) * 4;
    int* col1 = (int*)w;  w += (size_t)NE * 4;
    int* col2 = (int*)w;  w += (size_t)NE * 4;
    float* dinv1 = (float*)w; w += (size_t)NN * 4;
    float* dinv2 = (float*)w; w += (size_t)NN * 4;

    float* s1 = out + 12800000L;
    float* s2 = out + 25600128L;

    k_init<<<dim3(256), 256, 0, stream>>>(cnt1, cnt2, fill1, fill2, s1, s2);
    k_count<<<dim3(1024), 256, 0, stream>>>(dst1, dst2, cnt1, cnt2);
    k_scan<<<dim3(2), 1024, 0, stream>>>(cnt1, cnt2, rp1, rp2);
    k_dinv<<<dim3(196), 256, 0, stream>>>(cnt1, cnt2, dinv1, dinv2);
    k_fill<<<dim3(1024), 256, 0, stream>>>(src1, dst1, src2, dst2, rp1, rp2,
                                           fill1, fill2, col1, col2);
    k_gemm<<<dim3(782, 4), 256, 0, stream>>>(x, W1, W2, mp1, mn1, mp2, mn2,
                                             perm1, perm2, dinv1, dinv2, xwi1, xwi2);
    k_agg<<<dim3(12500, 2), 256, 0, stream>>>(xwi1, xwi2,
                                              rp1, col1, dinv1, rp2, col2, dinv2,
                                              b1, b2, out);
}

// Round 4
// 729.249 us; speedup vs baseline: 1.3745x; 1.2935x over previous
//
#include <hip/hip_runtime.h>
#include <hip/hip_fp16.h>

#define NN 50000
#define NE 800000
#define D 128

typedef _Float16 half8_t __attribute__((ext_vector_type(8)));
typedef _Float16 half4_t __attribute__((ext_vector_type(4)));
typedef float f32x4 __attribute__((ext_vector_type(4)));

// ---------------- K0: init counters + summary slots ----------------
__global__ void k_init(int* cnt1, int* cnt2, float* s1, float* s2) {
    int i = blockIdx.x * blockDim.x + threadIdx.x;
    int stride = gridDim.x * blockDim.x;
    for (int j = i; j < NN; j += stride) { cnt1[j] = 0; cnt2[j] = 0; }
    if (i < D) { s1[i] = 0.f; s2[i] = 0.f; }
}

// ---------------- K1: in-degree histogram (both graphs) ----------------
__global__ void k_count(const int* dst1, const int* dst2, int* cnt1, int* cnt2) {
    int i = blockIdx.x * blockDim.x + threadIdx.x;
    int stride = gridDim.x * blockDim.x;
    for (int e = i; e < NE; e += stride) {
        atomicAdd(&cnt1[dst1[e]], 1);
        atomicAdd(&cnt2[dst2[e]], 1);
    }
}

// ---------------- K2: scan -> row_ptr + cursor copy + dinv (one block per graph) ----------------
__global__ void k_scan(const int* cnt1, const int* cnt2, int* rp1, int* rp2,
                       int* cur1, int* cur2, float* dinv1, float* dinv2) {
    const int* cnt = blockIdx.x ? cnt2 : cnt1;
    int* rp = blockIdx.x ? rp2 : rp1;
    int* cur = blockIdx.x ? cur2 : cur1;
    float* dinv = blockIdx.x ? dinv2 : dinv1;
    __shared__ int part[1024];
    int t = threadIdx.x;
    const int CH = 49;  // 1024*49 = 50176 >= NN
    int base = t * CH;
    int local = 0;
    for (int k = 0; k < CH; k++) {
        int idx = base + k;
        if (idx < NN) local += cnt[idx];
    }
    part[t] = local;
    __syncthreads();
    for (int off = 1; off < 1024; off <<= 1) {
        int v = 0;
        if (t >= off) v = part[t - off];
        __syncthreads();
        part[t] += v;
        __syncthreads();
    }
    int run = part[t] - local;  // exclusive prefix
    for (int k = 0; k < CH; k++) {
        int idx = base + k;
        if (idx < NN) {
            rp[idx] = run;
            cur[idx] = run;
            dinv[idx] = rsqrtf((float)(cnt[idx] + 1));
            run += cnt[idx];
        }
    }
    if (t == 1023) rp[NN] = part[1023];
}

// ---------------- K3: CSR fill via cursor ----------------
__global__ void k_fill(const int* src1, const int* dst1,
                       const int* src2, const int* dst2,
                       int* cur1, int* cur2, int* col1, int* col2) {
    int i = blockIdx.x * blockDim.x + threadIdx.x;
    int stride = gridDim.x * blockDim.x;
    for (int e = i; e < NE; e += stride) {
        { int p = atomicAdd(&cur1[dst1[e]], 1); col1[p] = src1[e]; }
        { int p = atomicAdd(&cur2[dst2[e]], 1); col2[p] = src2[e]; }
    }
}

// ---------------- K4: 4 fused GEMMs (x*mask)@W -> dinv-prescaled f16, interleaved ----------------
// blockIdx.y: 0 = pos1, 1 = neg1 (rows gathered by perm1), 2 = pos2, 3 = neg2
// Output row layout: xwi[i][0:128] = pos, xwi[i][128:256] = neg, pre-scaled by dinv[i].
__launch_bounds__(256)
__global__ void k_gemm(const float* __restrict__ x,
                       const float* __restrict__ W1, const float* __restrict__ W2,
                       const float* __restrict__ mp1, const float* __restrict__ mn1,
                       const float* __restrict__ mp2, const float* __restrict__ mn2,
                       const int* __restrict__ perm1, const int* __restrict__ perm2,
                       const float* __restrict__ dinv1, const float* __restrict__ dinv2,
                       _Float16* xwi1, _Float16* xwi2) {
    int which = blockIdx.y;
    const float* W = (which < 2) ? W1 : W2;
    const float* mask = (which == 0) ? mp1 : (which == 1) ? mn1 : (which == 2) ? mp2 : mn2;
    const int* perm = (which == 1) ? perm1 : (which == 3) ? perm2 : nullptr;
    const float* dinv = (which < 2) ? dinv1 : dinv2;
    _Float16* out = ((which < 2) ? xwi1 : xwi2) + ((which & 1) ? 128 : 0);

    __shared__ __align__(16) _Float16 WT[128][136];
    int t = threadIdx.x;
    for (int i = 0; i < 16; i++) {
        int idx = i * 256 + t;
        int k = idx >> 5;
        int j4 = (idx & 31) * 4;
        float4 w = ((const float4*)W)[idx];
        WT[j4 + 0][k] = (_Float16)w.x;
        WT[j4 + 1][k] = (_Float16)w.y;
        WT[j4 + 2][k] = (_Float16)w.z;
        WT[j4 + 3][k] = (_Float16)w.w;
    }
    __syncthreads();

    int wave = t >> 6;
    int lane = t & 63;
    int quad = lane >> 4;
    int m = lane & 15;
    int tile = blockIdx.x * 4 + wave;
    if (tile * 16 >= NN) return;

    int row = tile * 16 + m;
    int grow = perm ? perm[row] : row;
    const float* xrow = x + (long)grow * D;
    const float* mrow = mask + (long)grow * D;

    half8_t a[4];
    for (int kk = 0; kk < 4; kk++) {
        int k0 = kk * 32 + quad * 8;
        float4 xa = *(const float4*)(xrow + k0);
        float4 xb = *(const float4*)(xrow + k0 + 4);
        float4 ma = *(const float4*)(mrow + k0);
        float4 mb = *(const float4*)(mrow + k0 + 4);
        a[kk][0] = (_Float16)(xa.x * ma.x);
        a[kk][1] = (_Float16)(xa.y * ma.y);
        a[kk][2] = (_Float16)(xa.z * ma.z);
        a[kk][3] = (_Float16)(xa.w * ma.w);
        a[kk][4] = (_Float16)(xb.x * mb.x);
        a[kk][5] = (_Float16)(xb.y * mb.y);
        a[kk][6] = (_Float16)(xb.z * mb.z);
        a[kk][7] = (_Float16)(xb.w * mb.w);
    }

    int rbase = tile * 16 + quad * 4;
    float ds0 = dinv[rbase + 0], ds1 = dinv[rbase + 1];
    float ds2 = dinv[rbase + 2], ds3 = dinv[rbase + 3];

    for (int nt = 0; nt < 8; nt++) {
        f32x4 acc = {0.f, 0.f, 0.f, 0.f};
        for (int kk = 0; kk < 4; kk++) {
            half8_t b = *(const half8_t*)(&WT[nt * 16 + m][kk * 32 + quad * 8]);
            acc = __builtin_amdgcn_mfma_f32_16x16x32_f16(a[kk], b, acc, 0, 0, 0);
        }
        int n = nt * 16 + m;
        out[(long)(rbase + 0) * 256 + n] = (_Float16)(acc[0] * ds0);
        out[(long)(rbase + 1) * 256 + n] = (_Float16)(acc[1] * ds1);
        out[(long)(rbase + 2) * 256 + n] = (_Float16)(acc[2] * ds2);
        out[(long)(rbase + 3) * 256 + n] = (_Float16)(acc[3] * ds3);
    }
}

// ---------------- K5: CSR gather aggregation + bias + ReLU (no atomics) ----------------
// wave per dst node; lanes 0-31 -> pos dims, lanes 32-63 -> neg dims.
__launch_bounds__(256)
__global__ void k_agg(const _Float16* __restrict__ xwi1, const _Float16* __restrict__ xwi2,
                      const int* __restrict__ rp1, const int* __restrict__ col1,
                      const float* __restrict__ dinv1,
                      const int* __restrict__ rp2, const int* __restrict__ col2,
                      const float* __restrict__ dinv2,
                      const float* __restrict__ b1, const float* __restrict__ b2,
                      float* out) {
    int g = blockIdx.y;
    const _Float16* xwi = g ? xwi2 : xwi1;
    const int* rp = g ? rp2 : rp1;
    const int* col = g ? col2 : col1;
    const float* dinv = g ? dinv2 : dinv1;
    const float* bias = g ? b2 : b1;
    float* pos_out = out + (g ? 12800128L : 0L);
    float* neg_out = out + (g ? 19200128L : 6400000L);

    int t = threadIdx.x;
    int wave = t >> 6, lane = t & 63;
    int i = blockIdx.x * 4 + wave;
    if (i >= NN) return;
    int j4 = lane * 4;  // half-index within the 256-half interleaved row

    half4_t sv = *(const half4_t*)(xwi + (long)i * 256 + j4);
    float a0 = (float)sv[0], a1 = (float)sv[1], a2 = (float)sv[2], a3 = (float)sv[3];
    int e0 = rp[i], e1 = rp[i + 1];
    int e = e0;
    for (; e + 8 <= e1; e += 8) {
        int s0 = col[e + 0], s1 = col[e + 1], s2 = col[e + 2], s3 = col[e + 3];
        int s4 = col[e + 4], s5 = col[e + 5], s6 = col[e + 6], s7 = col[e + 7];
        half4_t v0 = *(const half4_t*)(xwi + (long)s0 * 256 + j4);
        half4_t v1 = *(const half4_t*)(xwi + (long)s1 * 256 + j4);
        half4_t v2 = *(const half4_t*)(xwi + (long)s2 * 256 + j4);
        half4_t v3 = *(const half4_t*)(xwi + (long)s3 * 256 + j4);
        half4_t v4 = *(const half4_t*)(xwi + (long)s4 * 256 + j4);
        half4_t v5 = *(const half4_t*)(xwi + (long)s5 * 256 + j4);
        half4_t v6 = *(const half4_t*)(xwi + (long)s6 * 256 + j4);
        half4_t v7 = *(const half4_t*)(xwi + (long)s7 * 256 + j4);
        a0 += (float)v0[0] + (float)v1[0] + (float)v2[0] + (float)v3[0]
            + (float)v4[0] + (float)v5[0] + (float)v6[0] + (float)v7[0];
        a1 += (float)v0[1] + (float)v1[1] + (float)v2[1] + (float)v3[1]
            + (float)v4[1] + (float)v5[1] + (float)v6[1] + (float)v7[1];
        a2 += (float)v0[2] + (float)v1[2] + (float)v2[2] + (float)v3[2]
            + (float)v4[2] + (float)v5[2] + (float)v6[2] + (float)v7[2];
        a3 += (float)v0[3] + (float)v1[3] + (float)v2[3] + (float)v3[3]
            + (float)v4[3] + (float)v5[3] + (float)v6[3] + (float)v7[3];
    }
    for (; e + 4 <= e1; e += 4) {
        int s0 = col[e + 0], s1 = col[e + 1], s2 = col[e + 2], s3 = col[e + 3];
        half4_t v0 = *(const half4_t*)(xwi + (long)s0 * 256 + j4);
        half4_t v1 = *(const half4_t*)(xwi + (long)s1 * 256 + j4);
        half4_t v2 = *(const half4_t*)(xwi + (long)s2 * 256 + j4);
        half4_t v3 = *(const half4_t*)(xwi + (long)s3 * 256 + j4);
        a0 += (float)v0[0] + (float)v1[0] + (float)v2[0] + (float)v3[0];
        a1 += (float)v0[1] + (float)v1[1] + (float)v2[1] + (float)v3[1];
        a2 += (float)v0[2] + (float)v1[2] + (float)v2[2] + (float)v3[2];
        a3 += (float)v0[3] + (float)v1[3] + (float)v2[3] + (float)v3[3];
    }
    for (; e < e1; e++) {
        int s = col[e];
        half4_t v = *(const half4_t*)(xwi + (long)s * 256 + j4);
        a0 += (float)v[0]; a1 += (float)v[1]; a2 += (float)v[2]; a3 += (float)v[3];
    }
    float di = dinv[i];
    int jj = (lane < 32) ? j4 : (j4 - 128);
    const f32x4* bp = (const f32x4*)(bias + jj);
    f32x4 bv = *bp;
    f32x4 o;
    o[0] = fmaxf(0.f, di * a0 + bv[0]);
    o[1] = fmaxf(0.f, di * a1 + bv[1]);
    o[2] = fmaxf(0.f, di * a2 + bv[2]);
    o[3] = fmaxf(0.f, di * a3 + bv[3]);
    float* dst = ((lane < 32) ? pos_out : neg_out) + (long)i * D + jj;
    __builtin_nontemporal_store(o, (f32x4*)dst);
}

// ---------------- K6: summary mean over pos_h ----------------
__launch_bounds__(256)
__global__ void k_sum(const float* __restrict__ pos1, const float* __restrict__ pos2,
                      float* s1, float* s2) {
    int g = blockIdx.y;
    const float* pos = g ? pos2 : pos1;
    float* s = g ? s2 : s1;
    int t = threadIdx.x;
    int rg = t >> 5;           // row group 0..7
    int j = (t & 31) * 4;      // dim
    float4 acc = {0.f, 0.f, 0.f, 0.f};
    for (int i = blockIdx.x * 8 + rg; i < NN; i += gridDim.x * 8) {
        float4 v = *(const float4*)(pos + (long)i * D + j);
        acc.x += v.x; acc.y += v.y; acc.z += v.z; acc.w += v.w;
    }
    __shared__ float sm[8][128];
    sm[rg][j + 0] = acc.x;
    sm[rg][j + 1] = acc.y;
    sm[rg][j + 2] = acc.z;
    sm[rg][j + 3] = acc.w;
    __syncthreads();
    if (t < 128) {
        float v = 0.f;
        for (int r = 0; r < 8; r++) v += sm[r][t];
        atomicAdd(&s[t], v * (1.0f / NN));
    }
}

extern "C" void kernel_launch(void* const* d_in, const int* in_sizes, int n_in,
                              void* d_out, int out_size, void* d_ws, size_t ws_size,
                              hipStream_t stream) {
    const float* x   = (const float*)d_in[0];
    const float* W1  = (const float*)d_in[1];
    const float* b1  = (const float*)d_in[2];
    const float* W2  = (const float*)d_in[3];
    const float* b2  = (const float*)d_in[4];
    const float* mp1 = (const float*)d_in[5];
    const float* mn1 = (const float*)d_in[6];
    const float* mp2 = (const float*)d_in[7];
    const float* mn2 = (const float*)d_in[8];
    const int* e1 = (const int*)d_in[9];
    const int* e2 = (const int*)d_in[10];
    const int* perm1 = (const int*)d_in[11];
    const int* perm2 = (const int*)d_in[12];
    const int* src1 = e1;       const int* dst1 = e1 + NE;
    const int* src2 = e2;       const int* dst2 = e2 + NE;
    float* out = (float*)d_out;

    // workspace carve
    char* w = (char*)d_ws;
    _Float16* xwi1 = (_Float16*)w; w += (size_t)NN * 256 * 2;  // 25.6 MB interleaved
    _Float16* xwi2 = (_Float16*)w; w += (size_t)NN * 256 * 2;
    int* cnt1 = (int*)w;  w += (size_t)NN * 4;
    int* cnt2 = (int*)w;  w += (size_t)NN * 4;
    int* cur1 = (int*)w;  w += (size_t)NN * 4;
    int* cur2 = (int*)w;  w += (size_t)NN * 4;
    int* rp1 = (int*)w;   w += (size_t)(NN + 4) * 4;
    int* rp2 = (int*)w;   w += (size_t)(NN + 4) * 4;
    int* col1 = (int*)w;  w += (size_t)NE * 4;
    int* col2 = (int*)w;  w += (size_t)NE * 4;
    float* dinv1 = (float*)w; w += (size_t)NN * 4;
    float* dinv2 = (float*)w; w += (size_t)NN * 4;

    float* s1 = out + 12800000L;
    float* s2 = out + 25600128L;
    const float* pos1 = out;
    const float* pos2 = out + 12800128L;

    k_init<<<dim3(256), 256, 0, stream>>>(cnt1, cnt2, s1, s2);
    k_count<<<dim3(1024), 256, 0, stream>>>(dst1, dst2, cnt1, cnt2);
    k_scan<<<dim3(2), 1024, 0, stream>>>(cnt1, cnt2, rp1, rp2, cur1, cur2, dinv1, dinv2);
    k_fill<<<dim3(1024), 256, 0, stream>>>(src1, dst1, src2, dst2, cur1, cur2, col1, col2);
    k_gemm<<<dim3(782, 4), 256, 0, stream>>>(x, W1, W2, mp1, mn1, mp2, mn2,
                                             perm1, perm2, dinv1, dinv2, xwi1, xwi2);
    k_agg<<<dim3(12500, 2), 256, 0, stream>>>(xwi1, xwi2,
                                              rp1, col1, dinv1, rp2, col2, dinv2,
                                              b1, b2, out);
    k_sum<<<dim3(128, 2), 256, 0, stream>>>(pos1, pos2, s1, s2);
}

// Round 5
// 591.169 us; speedup vs baseline: 1.6955x; 1.2336x over previous
//
#include <hip/hip_runtime.h>
#include <hip/hip_fp16.h>

#define NN 50000
#define NE 800000
#define D 128
#define NB 196   // ceil(50000/256)

typedef _Float16 half8_t __attribute__((ext_vector_type(8)));
typedef _Float16 half4_t __attribute__((ext_vector_type(4)));
typedef float f32x4 __attribute__((ext_vector_type(4)));

// ---------------- K0: init counters + summary slots ----------------
__global__ void k_init(int* cnt1, int* cnt2, float* s1, float* s2) {
    int i = blockIdx.x * blockDim.x + threadIdx.x;
    int stride = gridDim.x * blockDim.x;
    for (int j = i; j < NN; j += stride) { cnt1[j] = 0; cnt2[j] = 0; }
    if (i < D) { s1[i] = 0.f; s2[i] = 0.f; }
}

// ---------------- K1: in-degree histogram (both graphs) ----------------
__global__ void k_count(const int* dst1, const int* dst2, int* cnt1, int* cnt2) {
    int i = blockIdx.x * blockDim.x + threadIdx.x;
    int stride = gridDim.x * blockDim.x;
    for (int e = i; e < NE; e += stride) {
        atomicAdd(&cnt1[dst1[e]], 1);
        atomicAdd(&cnt2[dst2[e]], 1);
    }
}

// ---------------- K2a: per-block partial sums of counts (both graphs) ----------------
__global__ void k_part(const int* __restrict__ cnt1, const int* __restrict__ cnt2,
                       int* part1, int* part2) {
    __shared__ int sm1[256], sm2[256];
    int t = threadIdx.x;
    int idx = blockIdx.x * 256 + t;
    int v1 = (idx < NN) ? cnt1[idx] : 0;
    int v2 = (idx < NN) ? cnt2[idx] : 0;
    sm1[t] = v1; sm2[t] = v2;
    __syncthreads();
    for (int off = 128; off > 0; off >>= 1) {
        if (t < off) { sm1[t] += sm1[t + off]; sm2[t] += sm2[t + off]; }
        __syncthreads();
    }
    if (t == 0) { part1[blockIdx.x] = sm1[0]; part2[blockIdx.x] = sm2[0]; }
}

// ---------------- K2b: exclusive scan of block partials (one block) ----------------
__global__ void k_scanp(int* part1, int* part2) {
    __shared__ int sm1[256], sm2[256];
    int t = threadIdx.x;
    int v1 = (t < NB) ? part1[t] : 0;
    int v2 = (t < NB) ? part2[t] : 0;
    sm1[t] = v1; sm2[t] = v2;
    __syncthreads();
    for (int off = 1; off < 256; off <<= 1) {
        int a1 = (t >= off) ? sm1[t - off] : 0;
        int a2 = (t >= off) ? sm2[t - off] : 0;
        __syncthreads();
        sm1[t] += a1; sm2[t] += a2;
        __syncthreads();
    }
    if (t < NB) { part1[t] = sm1[t] - v1; part2[t] = sm2[t] - v2; }
}

// ---------------- K2c: apply block offsets -> rp, cur, dinv ----------------
__global__ void k_apply(const int* __restrict__ cnt1, const int* __restrict__ cnt2,
                        const int* __restrict__ part1, const int* __restrict__ part2,
                        int* rp1, int* rp2, int* cur1, int* cur2,
                        float* dinv1, float* dinv2) {
    __shared__ int sm1[256], sm2[256];
    int b = blockIdx.x, t = threadIdx.x;
    int idx = b * 256 + t;
    int v1 = (idx < NN) ? cnt1[idx] : 0;
    int v2 = (idx < NN) ? cnt2[idx] : 0;
    sm1[t] = v1; sm2[t] = v2;
    __syncthreads();
    for (int off = 1; off < 256; off <<= 1) {
        int a1 = (t >= off) ? sm1[t - off] : 0;
        int a2 = (t >= off) ? sm2[t - off] : 0;
        __syncthreads();
        sm1[t] += a1; sm2[t] += a2;
        __syncthreads();
    }
    int e1 = sm1[t] - v1 + part1[b];  // exclusive prefix
    int e2 = sm2[t] - v2 + part2[b];
    if (idx < NN) {
        rp1[idx] = e1; cur1[idx] = e1; dinv1[idx] = rsqrtf((float)(v1 + 1));
        rp2[idx] = e2; cur2[idx] = e2; dinv2[idx] = rsqrtf((float)(v2 + 1));
    } else if (idx == NN) {
        rp1[NN] = e1; rp2[NN] = e2;
    }
}

// ---------------- K3: CSR fill via cursor ----------------
__global__ void k_fill(const int* src1, const int* dst1,
                       const int* src2, const int* dst2,
                       int* cur1, int* cur2, int* col1, int* col2) {
    int i = blockIdx.x * blockDim.x + threadIdx.x;
    int stride = gridDim.x * blockDim.x;
    for (int e = i; e < NE; e += stride) {
        { int p = atomicAdd(&cur1[dst1[e]], 1); col1[p] = src1[e]; }
        { int p = atomicAdd(&cur2[dst2[e]], 1); col2[p] = src2[e]; }
    }
}

// ---------------- K4: 4 fused GEMMs (x*mask)@W -> dinv-prescaled f16, interleaved ----------------
__launch_bounds__(256)
__global__ void k_gemm(const float* __restrict__ x,
                       const float* __restrict__ W1, const float* __restrict__ W2,
                       const float* __restrict__ mp1, const float* __restrict__ mn1,
                       const float* __restrict__ mp2, const float* __restrict__ mn2,
                       const int* __restrict__ perm1, const int* __restrict__ perm2,
                       const float* __restrict__ dinv1, const float* __restrict__ dinv2,
                       _Float16* xwi1, _Float16* xwi2) {
    int which = blockIdx.y;
    const float* W = (which < 2) ? W1 : W2;
    const float* mask = (which == 0) ? mp1 : (which == 1) ? mn1 : (which == 2) ? mp2 : mn2;
    const int* perm = (which == 1) ? perm1 : (which == 3) ? perm2 : nullptr;
    const float* dinv = (which < 2) ? dinv1 : dinv2;
    _Float16* out = ((which < 2) ? xwi1 : xwi2) + ((which & 1) ? 128 : 0);

    __shared__ __align__(16) _Float16 WT[128][136];
    int t = threadIdx.x;
    for (int i = 0; i < 16; i++) {
        int idx = i * 256 + t;
        int k = idx >> 5;
        int j4 = (idx & 31) * 4;
        float4 w = ((const float4*)W)[idx];
        WT[j4 + 0][k] = (_Float16)w.x;
        WT[j4 + 1][k] = (_Float16)w.y;
        WT[j4 + 2][k] = (_Float16)w.z;
        WT[j4 + 3][k] = (_Float16)w.w;
    }
    __syncthreads();

    int wave = t >> 6;
    int lane = t & 63;
    int quad = lane >> 4;
    int m = lane & 15;
    int tile = blockIdx.x * 4 + wave;
    if (tile * 16 >= NN) return;

    int row = tile * 16 + m;
    int grow = perm ? perm[row] : row;
    const float* xrow = x + (long)grow * D;
    const float* mrow = mask + (long)grow * D;

    half8_t a[4];
    for (int kk = 0; kk < 4; kk++) {
        int k0 = kk * 32 + quad * 8;
        float4 xa = *(const float4*)(xrow + k0);
        float4 xb = *(const float4*)(xrow + k0 + 4);
        float4 ma = *(const float4*)(mrow + k0);
        float4 mb = *(const float4*)(mrow + k0 + 4);
        a[kk][0] = (_Float16)(xa.x * ma.x);
        a[kk][1] = (_Float16)(xa.y * ma.y);
        a[kk][2] = (_Float16)(xa.z * ma.z);
        a[kk][3] = (_Float16)(xa.w * ma.w);
        a[kk][4] = (_Float16)(xb.x * mb.x);
        a[kk][5] = (_Float16)(xb.y * mb.y);
        a[kk][6] = (_Float16)(xb.z * mb.z);
        a[kk][7] = (_Float16)(xb.w * mb.w);
    }

    int rbase = tile * 16 + quad * 4;
    float ds0 = dinv[rbase + 0], ds1 = dinv[rbase + 1];
    float ds2 = dinv[rbase + 2], ds3 = dinv[rbase + 3];

    for (int nt = 0; nt < 8; nt++) {
        f32x4 acc = {0.f, 0.f, 0.f, 0.f};
        for (int kk = 0; kk < 4; kk++) {
            half8_t b = *(const half8_t*)(&WT[nt * 16 + m][kk * 32 + quad * 8]);
            acc = __builtin_amdgcn_mfma_f32_16x16x32_f16(a[kk], b, acc, 0, 0, 0);
        }
        int n = nt * 16 + m;
        out[(long)(rbase + 0) * 256 + n] = (_Float16)(acc[0] * ds0);
        out[(long)(rbase + 1) * 256 + n] = (_Float16)(acc[1] * ds1);
        out[(long)(rbase + 2) * 256 + n] = (_Float16)(acc[2] * ds2);
        out[(long)(rbase + 3) * 256 + n] = (_Float16)(acc[3] * ds3);
    }
}

// ---------------- K5: CSR gather aggregation + bias + ReLU (no atomics) ----------------
__launch_bounds__(256)
__global__ void k_agg(const _Float16* __restrict__ xwi1, const _Float16* __restrict__ xwi2,
                      const int* __restrict__ rp1, const int* __restrict__ col1,
                      const float* __restrict__ dinv1,
                      const int* __restrict__ rp2, const int* __restrict__ col2,
                      const float* __restrict__ dinv2,
                      const float* __restrict__ b1, const float* __restrict__ b2,
                      float* out) {
    int g = blockIdx.y;
    const _Float16* xwi = g ? xwi2 : xwi1;
    const int* rp = g ? rp2 : rp1;
    const int* col = g ? col2 : col1;
    const float* dinv = g ? dinv2 : dinv1;
    const float* bias = g ? b2 : b1;
    float* pos_out = out + (g ? 12800128L : 0L);
    float* neg_out = out + (g ? 19200128L : 6400000L);

    int t = threadIdx.x;
    int wave = t >> 6, lane = t & 63;
    int i = blockIdx.x * 4 + wave;
    if (i >= NN) return;
    int j4 = lane * 4;

    half4_t sv = *(const half4_t*)(xwi + (long)i * 256 + j4);
    float a0 = (float)sv[0], a1 = (float)sv[1], a2 = (float)sv[2], a3 = (float)sv[3];
    int e0 = rp[i], e1 = rp[i + 1];
    int e = e0;
    for (; e + 8 <= e1; e += 8) {
        int s0 = col[e + 0], s1 = col[e + 1], s2 = col[e + 2], s3 = col[e + 3];
        int s4 = col[e + 4], s5 = col[e + 5], s6 = col[e + 6], s7 = col[e + 7];
        half4_t v0 = *(const half4_t*)(xwi + (long)s0 * 256 + j4);
        half4_t v1 = *(const half4_t*)(xwi + (long)s1 * 256 + j4);
        half4_t v2 = *(const half4_t*)(xwi + (long)s2 * 256 + j4);
        half4_t v3 = *(const half4_t*)(xwi + (long)s3 * 256 + j4);
        half4_t v4 = *(const half4_t*)(xwi + (long)s4 * 256 + j4);
        half4_t v5 = *(const half4_t*)(xwi + (long)s5 * 256 + j4);
        half4_t v6 = *(const half4_t*)(xwi + (long)s6 * 256 + j4);
        half4_t v7 = *(const half4_t*)(xwi + (long)s7 * 256 + j4);
        a0 += (float)v0[0] + (float)v1[0] + (float)v2[0] + (float)v3[0]
            + (float)v4[0] + (float)v5[0] + (float)v6[0] + (float)v7[0];
        a1 += (float)v0[1] + (float)v1[1] + (float)v2[1] + (float)v3[1]
            + (float)v4[1] + (float)v5[1] + (float)v6[1] + (float)v7[1];
        a2 += (float)v0[2] + (float)v1[2] + (float)v2[2] + (float)v3[2]
            + (float)v4[2] + (float)v5[2] + (float)v6[2] + (float)v7[2];
        a3 += (float)v0[3] + (float)v1[3] + (float)v2[3] + (float)v3[3]
            + (float)v4[3] + (float)v5[3] + (float)v6[3] + (float)v7[3];
    }
    for (; e + 4 <= e1; e += 4) {
        int s0 = col[e + 0], s1 = col[e + 1], s2 = col[e + 2], s3 = col[e + 3];
        half4_t v0 = *(const half4_t*)(xwi + (long)s0 * 256 + j4);
        half4_t v1 = *(const half4_t*)(xwi + (long)s1 * 256 + j4);
        half4_t v2 = *(const half4_t*)(xwi + (long)s2 * 256 + j4);
        half4_t v3 = *(const half4_t*)(xwi + (long)s3 * 256 + j4);
        a0 += (float)v0[0] + (float)v1[0] + (float)v2[0] + (float)v3[0];
        a1 += (float)v0[1] + (float)v1[1] + (float)v2[1] + (float)v3[1];
        a2 += (float)v0[2] + (float)v1[2] + (float)v2[2] + (float)v3[2];
        a3 += (float)v0[3] + (float)v1[3] + (float)v2[3] + (float)v3[3];
    }
    for (; e < e1; e++) {
        int s = col[e];
        half4_t v = *(const half4_t*)(xwi + (long)s * 256 + j4);
        a0 += (float)v[0]; a1 += (float)v[1]; a2 += (float)v[2]; a3 += (float)v[3];
    }
    float di = dinv[i];
    int jj = (lane < 32) ? j4 : (j4 - 128);
    const f32x4* bp = (const f32x4*)(bias + jj);
    f32x4 bv = *bp;
    f32x4 o;
    o[0] = fmaxf(0.f, di * a0 + bv[0]);
    o[1] = fmaxf(0.f, di * a1 + bv[1]);
    o[2] = fmaxf(0.f, di * a2 + bv[2]);
    o[3] = fmaxf(0.f, di * a3 + bv[3]);
    float* dst = ((lane < 32) ? pos_out : neg_out) + (long)i * D + jj;
    __builtin_nontemporal_store(o, (f32x4*)dst);
}

// ---------------- K6: summary mean over pos_h ----------------
__launch_bounds__(256)
__global__ void k_sum(const float* __restrict__ pos1, const float* __restrict__ pos2,
                      float* s1, float* s2) {
    int g = blockIdx.y;
    const float* pos = g ? pos2 : pos1;
    float* s = g ? s2 : s1;
    int t = threadIdx.x;
    int rg = t >> 5;
    int j = (t & 31) * 4;
    float4 acc = {0.f, 0.f, 0.f, 0.f};
    for (int i = blockIdx.x * 8 + rg; i < NN; i += gridDim.x * 8) {
        float4 v = *(const float4*)(pos + (long)i * D + j);
        acc.x += v.x; acc.y += v.y; acc.z += v.z; acc.w += v.w;
    }
    __shared__ float sm[8][128];
    sm[rg][j + 0] = acc.x;
    sm[rg][j + 1] = acc.y;
    sm[rg][j + 2] = acc.z;
    sm[rg][j + 3] = acc.w;
    __syncthreads();
    if (t < 128) {
        float v = 0.f;
        for (int r = 0; r < 8; r++) v += sm[r][t];
        atomicAdd(&s[t], v * (1.0f / NN));
    }
}

extern "C" void kernel_launch(void* const* d_in, const int* in_sizes, int n_in,
                              void* d_out, int out_size, void* d_ws, size_t ws_size,
                              hipStream_t stream) {
    const float* x   = (const float*)d_in[0];
    const float* W1  = (const float*)d_in[1];
    const float* b1  = (const float*)d_in[2];
    const float* W2  = (const float*)d_in[3];
    const float* b2  = (const float*)d_in[4];
    const float* mp1 = (const float*)d_in[5];
    const float* mn1 = (const float*)d_in[6];
    const float* mp2 = (const float*)d_in[7];
    const float* mn2 = (const float*)d_in[8];
    const int* e1 = (const int*)d_in[9];
    const int* e2 = (const int*)d_in[10];
    const int* perm1 = (const int*)d_in[11];
    const int* perm2 = (const int*)d_in[12];
    const int* src1 = e1;       const int* dst1 = e1 + NE;
    const int* src2 = e2;       const int* dst2 = e2 + NE;
    float* out = (float*)d_out;

    // workspace carve
    char* w = (char*)d_ws;
    _Float16* xwi1 = (_Float16*)w; w += (size_t)NN * 256 * 2;  // 25.6 MB interleaved
    _Float16* xwi2 = (_Float16*)w; w += (size_t)NN * 256 * 2;
    int* cnt1 = (int*)w;  w += (size_t)NN * 4;
    int* cnt2 = (int*)w;  w += (size_t)NN * 4;
    int* cur1 = (int*)w;  w += (size_t)NN * 4;
    int* cur2 = (int*)w;  w += (size_t)NN * 4;
    int* rp1 = (int*)w;   w += (size_t)(NN + 4) * 4;
    int* rp2 = (int*)w;   w += (size_t)(NN + 4) * 4;
    int* col1 = (int*)w;  w += (size_t)NE * 4;
    int* col2 = (int*)w;  w += (size_t)NE * 4;
    float* dinv1 = (float*)w; w += (size_t)NN * 4;
    float* dinv2 = (float*)w; w += (size_t)NN * 4;
    int* part1 = (int*)w; w += (size_t)256 * 4;
    int* part2 = (int*)w; w += (size_t)256 * 4;

    float* s1 = out + 12800000L;
    float* s2 = out + 25600128L;
    const float* pos1 = out;
    const float* pos2 = out + 12800128L;

    k_init<<<dim3(256), 256, 0, stream>>>(cnt1, cnt2, s1, s2);
    k_count<<<dim3(1024), 256, 0, stream>>>(dst1, dst2, cnt1, cnt2);
    k_part<<<dim3(NB), 256, 0, stream>>>(cnt1, cnt2, part1, part2);
    k_scanp<<<dim3(1), 256, 0, stream>>>(part1, part2);
    k_apply<<<dim3(NB), 256, 0, stream>>>(cnt1, cnt2, part1, part2,
                                          rp1, rp2, cur1, cur2, dinv1, dinv2);
    k_fill<<<dim3(1024), 256, 0, stream>>>(src1, dst1, src2, dst2, cur1, cur2, col1, col2);
    k_gemm<<<dim3(782, 4), 256, 0, stream>>>(x, W1, W2, mp1, mn1, mp2, mn2,
                                             perm1, perm2, dinv1, dinv2, xwi1, xwi2);
    k_agg<<<dim3(12500, 2), 256, 0, stream>>>(xwi1, xwi2,
                                              rp1, col1, dinv1, rp2, col2, dinv2,
                                              b1, b2, out);
    k_sum<<<dim3(128, 2), 256, 0, stream>>>(pos1, pos2, s1, s2);
}

// Round 6
// 553.664 us; speedup vs baseline: 1.8104x; 1.0677x over previous
//
#include <hip/hip_runtime.h>
#include <hip/hip_fp16.h>

#define NN 50000
#define NE 800000
#define D 128
#define NB 196        // ceil(50000/256)
#define FILL_BLOCKS 1024
#define GEMM_BLOCKS 3128   // 782 * 4

typedef _Float16 half8_t __attribute__((ext_vector_type(8)));
typedef _Float16 half4_t __attribute__((ext_vector_type(4)));
typedef float f32x4 __attribute__((ext_vector_type(4)));

// ---------------- K0: init counters + summary slots ----------------
__global__ void k_init(int* cnt1, int* cnt2, float* s1, float* s2) {
    int i = blockIdx.x * blockDim.x + threadIdx.x;
    int stride = gridDim.x * blockDim.x;
    for (int j = i; j < NN; j += stride) { cnt1[j] = 0; cnt2[j] = 0; }
    if (i < D) { s1[i] = 0.f; s2[i] = 0.f; }
}

// ---------------- K1: in-degree histogram (both graphs) ----------------
__global__ void k_count(const int* dst1, const int* dst2, int* cnt1, int* cnt2) {
    int i = blockIdx.x * blockDim.x + threadIdx.x;
    int stride = gridDim.x * blockDim.x;
    for (int e = i; e < NE; e += stride) {
        atomicAdd(&cnt1[dst1[e]], 1);
        atomicAdd(&cnt2[dst2[e]], 1);
    }
}

// ---------------- K2a: per-block partial sums of counts (both graphs) ----------------
__global__ void k_part(const int* __restrict__ cnt1, const int* __restrict__ cnt2,
                       int* part1, int* part2) {
    __shared__ int sm1[256], sm2[256];
    int t = threadIdx.x;
    int idx = blockIdx.x * 256 + t;
    int v1 = (idx < NN) ? cnt1[idx] : 0;
    int v2 = (idx < NN) ? cnt2[idx] : 0;
    sm1[t] = v1; sm2[t] = v2;
    __syncthreads();
    for (int off = 128; off > 0; off >>= 1) {
        if (t < off) { sm1[t] += sm1[t + off]; sm2[t] += sm2[t + off]; }
        __syncthreads();
    }
    if (t == 0) { part1[blockIdx.x] = sm1[0]; part2[blockIdx.x] = sm2[0]; }
}

// ---------------- K2b: exclusive scan of block partials (one block) ----------------
__global__ void k_scanp(int* part1, int* part2) {
    __shared__ int sm1[256], sm2[256];
    int t = threadIdx.x;
    int v1 = (t < NB) ? part1[t] : 0;
    int v2 = (t < NB) ? part2[t] : 0;
    sm1[t] = v1; sm2[t] = v2;
    __syncthreads();
    for (int off = 1; off < 256; off <<= 1) {
        int a1 = (t >= off) ? sm1[t - off] : 0;
        int a2 = (t >= off) ? sm2[t - off] : 0;
        __syncthreads();
        sm1[t] += a1; sm2[t] += a2;
        __syncthreads();
    }
    if (t < NB) { part1[t] = sm1[t] - v1; part2[t] = sm2[t] - v2; }
}

// ---------------- K2c: apply block offsets -> rp, cur, dinv ----------------
__global__ void k_apply(const int* __restrict__ cnt1, const int* __restrict__ cnt2,
                        const int* __restrict__ part1, const int* __restrict__ part2,
                        int* rp1, int* rp2, int* cur1, int* cur2,
                        float* dinv1, float* dinv2) {
    __shared__ int sm1[256], sm2[256];
    int b = blockIdx.x, t = threadIdx.x;
    int idx = b * 256 + t;
    int v1 = (idx < NN) ? cnt1[idx] : 0;
    int v2 = (idx < NN) ? cnt2[idx] : 0;
    sm1[t] = v1; sm2[t] = v2;
    __syncthreads();
    for (int off = 1; off < 256; off <<= 1) {
        int a1 = (t >= off) ? sm1[t - off] : 0;
        int a2 = (t >= off) ? sm2[t - off] : 0;
        __syncthreads();
        sm1[t] += a1; sm2[t] += a2;
        __syncthreads();
    }
    int e1 = sm1[t] - v1 + part1[b];  // exclusive prefix
    int e2 = sm2[t] - v2 + part2[b];
    if (idx < NN) {
        rp1[idx] = e1; cur1[idx] = e1; dinv1[idx] = rsqrtf((float)(v1 + 1));
        rp2[idx] = e2; cur2[idx] = e2; dinv2[idx] = rsqrtf((float)(v2 + 1));
    } else if (idx == NN) {
        rp1[NN] = e1; rp2[NN] = e2;
    }
}

// ---------------- K3+K4 merged: CSR fill (blocks 0..1023) + 4 GEMMs (blocks 1024..) ----
// Fill blocks are latency-bound with all pipes idle; gemm blocks co-resident on the
// same CUs absorb the idle issue slots with MFMA/VALU work.
__launch_bounds__(256)
__global__ void k_fill_gemm(const int* __restrict__ src1, const int* __restrict__ dst1,
                            const int* __restrict__ src2, const int* __restrict__ dst2,
                            int* cur1, int* cur2, int* col1, int* col2,
                            const float* __restrict__ x,
                            const float* __restrict__ W1, const float* __restrict__ W2,
                            const float* __restrict__ mp1, const float* __restrict__ mn1,
                            const float* __restrict__ mp2, const float* __restrict__ mn2,
                            const int* __restrict__ perm1, const int* __restrict__ perm2,
                            const float* __restrict__ dinv1, const float* __restrict__ dinv2,
                            _Float16* xwi1, _Float16* xwi2) {
    __shared__ __align__(16) _Float16 WT[128][136];
    int t = threadIdx.x;

    if (blockIdx.x < FILL_BLOCKS) {
        // ---- CSR fill via cursor ----
        int i = blockIdx.x * 256 + t;
        int stride = FILL_BLOCKS * 256;
        for (int e = i; e < NE; e += stride) {
            { int p = atomicAdd(&cur1[dst1[e]], 1); col1[p] = src1[e]; }
            { int p = atomicAdd(&cur2[dst2[e]], 1); col2[p] = src2[e]; }
        }
        return;
    }

    // ---- GEMM part ----
    int g = blockIdx.x - FILL_BLOCKS;      // 0..3127
    int which = g / 782;                   // 0 = pos1, 1 = neg1, 2 = pos2, 3 = neg2
    int bx = g - which * 782;
    const float* W = (which < 2) ? W1 : W2;
    const float* mask = (which == 0) ? mp1 : (which == 1) ? mn1 : (which == 2) ? mp2 : mn2;
    const int* perm = (which == 1) ? perm1 : (which == 3) ? perm2 : nullptr;
    const float* dinv = (which < 2) ? dinv1 : dinv2;
    _Float16* out = ((which < 2) ? xwi1 : xwi2) + ((which & 1) ? 128 : 0);

    for (int i = 0; i < 16; i++) {
        int idx = i * 256 + t;
        int k = idx >> 5;
        int j4 = (idx & 31) * 4;
        float4 w = ((const float4*)W)[idx];
        WT[j4 + 0][k] = (_Float16)w.x;
        WT[j4 + 1][k] = (_Float16)w.y;
        WT[j4 + 2][k] = (_Float16)w.z;
        WT[j4 + 3][k] = (_Float16)w.w;
    }
    __syncthreads();

    int wave = t >> 6;
    int lane = t & 63;
    int quad = lane >> 4;
    int m = lane & 15;
    int tile = bx * 4 + wave;
    if (tile * 16 >= NN) return;

    int row = tile * 16 + m;
    int grow = perm ? perm[row] : row;
    const float* xrow = x + (long)grow * D;
    const float* mrow = mask + (long)grow * D;

    half8_t a[4];
    for (int kk = 0; kk < 4; kk++) {
        int k0 = kk * 32 + quad * 8;
        float4 xa = *(const float4*)(xrow + k0);
        float4 xb = *(const float4*)(xrow + k0 + 4);
        float4 ma = *(const float4*)(mrow + k0);
        float4 mb = *(const float4*)(mrow + k0 + 4);
        a[kk][0] = (_Float16)(xa.x * ma.x);
        a[kk][1] = (_Float16)(xa.y * ma.y);
        a[kk][2] = (_Float16)(xa.z * ma.z);
        a[kk][3] = (_Float16)(xa.w * ma.w);
        a[kk][4] = (_Float16)(xb.x * mb.x);
        a[kk][5] = (_Float16)(xb.y * mb.y);
        a[kk][6] = (_Float16)(xb.z * mb.z);
        a[kk][7] = (_Float16)(xb.w * mb.w);
    }

    int rbase = tile * 16 + quad * 4;
    float ds0 = dinv[rbase + 0], ds1 = dinv[rbase + 1];
    float ds2 = dinv[rbase + 2], ds3 = dinv[rbase + 3];

    for (int nt = 0; nt < 8; nt++) {
        f32x4 acc = {0.f, 0.f, 0.f, 0.f};
        for (int kk = 0; kk < 4; kk++) {
            half8_t b = *(const half8_t*)(&WT[nt * 16 + m][kk * 32 + quad * 8]);
            acc = __builtin_amdgcn_mfma_f32_16x16x32_f16(a[kk], b, acc, 0, 0, 0);
        }
        int n = nt * 16 + m;
        out[(long)(rbase + 0) * 256 + n] = (_Float16)(acc[0] * ds0);
        out[(long)(rbase + 1) * 256 + n] = (_Float16)(acc[1] * ds1);
        out[(long)(rbase + 2) * 256 + n] = (_Float16)(acc[2] * ds2);
        out[(long)(rbase + 3) * 256 + n] = (_Float16)(acc[3] * ds3);
    }
}

// ---------------- K5: CSR gather aggregation + bias + ReLU (no atomics) ----------------
__launch_bounds__(256)
__global__ void k_agg(const _Float16* __restrict__ xwi1, const _Float16* __restrict__ xwi2,
                      const int* __restrict__ rp1, const int* __restrict__ col1,
                      const float* __restrict__ dinv1,
                      const int* __restrict__ rp2, const int* __restrict__ col2,
                      const float* __restrict__ dinv2,
                      const float* __restrict__ b1, const float* __restrict__ b2,
                      float* out) {
    int g = blockIdx.y;
    const _Float16* xwi = g ? xwi2 : xwi1;
    const int* rp = g ? rp2 : rp1;
    const int* col = g ? col2 : col1;
    const float* dinv = g ? dinv2 : dinv1;
    const float* bias = g ? b2 : b1;
    float* pos_out = out + (g ? 12800128L : 0L);
    float* neg_out = out + (g ? 19200128L : 6400000L);

    int t = threadIdx.x;
    int wave = t >> 6, lane = t & 63;
    int i = blockIdx.x * 4 + wave;
    if (i >= NN) return;
    int j4 = lane * 4;

    half4_t sv = *(const half4_t*)(xwi + (long)i * 256 + j4);
    float a0 = (float)sv[0], a1 = (float)sv[1], a2 = (float)sv[2], a3 = (float)sv[3];
    int e0 = rp[i], e1 = rp[i + 1];
    int e = e0;
    for (; e + 8 <= e1; e += 8) {
        int s0 = col[e + 0], s1 = col[e + 1], s2 = col[e + 2], s3 = col[e + 3];
        int s4 = col[e + 4], s5 = col[e + 5], s6 = col[e + 6], s7 = col[e + 7];
        half4_t v0 = *(const half4_t*)(xwi + (long)s0 * 256 + j4);
        half4_t v1 = *(const half4_t*)(xwi + (long)s1 * 256 + j4);
        half4_t v2 = *(const half4_t*)(xwi + (long)s2 * 256 + j4);
        half4_t v3 = *(const half4_t*)(xwi + (long)s3 * 256 + j4);
        half4_t v4 = *(const half4_t*)(xwi + (long)s4 * 256 + j4);
        half4_t v5 = *(const half4_t*)(xwi + (long)s5 * 256 + j4);
        half4_t v6 = *(const half4_t*)(xwi + (long)s6 * 256 + j4);
        half4_t v7 = *(const half4_t*)(xwi + (long)s7 * 256 + j4);
        a0 += (float)v0[0] + (float)v1[0] + (float)v2[0] + (float)v3[0]
            + (float)v4[0] + (float)v5[0] + (float)v6[0] + (float)v7[0];
        a1 += (float)v0[1] + (float)v1[1] + (float)v2[1] + (float)v3[1]
            + (float)v4[1] + (float)v5[1] + (float)v6[1] + (float)v7[1];
        a2 += (float)v0[2] + (float)v1[2] + (float)v2[2] + (float)v3[2]
            + (float)v4[2] + (float)v5[2] + (float)v6[2] + (float)v7[2];
        a3 += (float)v0[3] + (float)v1[3] + (float)v2[3] + (float)v3[3]
            + (float)v4[3] + (float)v5[3] + (float)v6[3] + (float)v7[3];
    }
    for (; e + 4 <= e1; e += 4) {
        int s0 = col[e + 0], s1 = col[e + 1], s2 = col[e + 2], s3 = col[e + 3];
        half4_t v0 = *(const half4_t*)(xwi + (long)s0 * 256 + j4);
        half4_t v1 = *(const half4_t*)(xwi + (long)s1 * 256 + j4);
        half4_t v2 = *(const half4_t*)(xwi + (long)s2 * 256 + j4);
        half4_t v3 = *(const half4_t*)(xwi + (long)s3 * 256 + j4);
        a0 += (float)v0[0] + (float)v1[0] + (float)v2[0] + (float)v3[0];
        a1 += (float)v0[1] + (float)v1[1] + (float)v2[1] + (float)v3[1];
        a2 += (float)v0[2] + (float)v1[2] + (float)v2[2] + (float)v3[2];
        a3 += (float)v0[3] + (float)v1[3] + (float)v2[3] + (float)v3[3];
    }
    for (; e < e1; e++) {
        int s = col[e];
        half4_t v = *(const half4_t*)(xwi + (long)s * 256 + j4);
        a0 += (float)v[0]; a1 += (float)v[1]; a2 += (float)v[2]; a3 += (float)v[3];
    }
    float di = dinv[i];
    int jj = (lane < 32) ? j4 : (j4 - 128);
    const f32x4* bp = (const f32x4*)(bias + jj);
    f32x4 bv = *bp;
    f32x4 o;
    o[0] = fmaxf(0.f, di * a0 + bv[0]);
    o[1] = fmaxf(0.f, di * a1 + bv[1]);
    o[2] = fmaxf(0.f, di * a2 + bv[2]);
    o[3] = fmaxf(0.f, di * a3 + bv[3]);
    float* dst = ((lane < 32) ? pos_out : neg_out) + (long)i * D + jj;
    __builtin_nontemporal_store(o, (f32x4*)dst);
}

// ---------------- K6: summary mean over pos_h ----------------
__launch_bounds__(256)
__global__ void k_sum(const float* __restrict__ pos1, const float* __restrict__ pos2,
                      float* s1, float* s2) {
    int g = blockIdx.y;
    const float* pos = g ? pos2 : pos1;
    float* s = g ? s2 : s1;
    int t = threadIdx.x;
    int rg = t >> 5;
    int j = (t & 31) * 4;
    float4 acc = {0.f, 0.f, 0.f, 0.f};
    for (int i = blockIdx.x * 8 + rg; i < NN; i += gridDim.x * 8) {
        float4 v = *(const float4*)(pos + (long)i * D + j);
        acc.x += v.x; acc.y += v.y; acc.z += v.z; acc.w += v.w;
    }
    __shared__ float sm[8][128];
    sm[rg][j + 0] = acc.x;
    sm[rg][j + 1] = acc.y;
    sm[rg][j + 2] = acc.z;
    sm[rg][j + 3] = acc.w;
    __syncthreads();
    if (t < 128) {
        float v = 0.f;
        for (int r = 0; r < 8; r++) v += sm[r][t];
        atomicAdd(&s[t], v * (1.0f / NN));
    }
}

extern "C" void kernel_launch(void* const* d_in, const int* in_sizes, int n_in,
                              void* d_out, int out_size, void* d_ws, size_t ws_size,
                              hipStream_t stream) {
    const float* x   = (const float*)d_in[0];
    const float* W1  = (const float*)d_in[1];
    const float* b1  = (const float*)d_in[2];
    const float* W2  = (const float*)d_in[3];
    const float* b2  = (const float*)d_in[4];
    const float* mp1 = (const float*)d_in[5];
    const float* mn1 = (const float*)d_in[6];
    const float* mp2 = (const float*)d_in[7];
    const float* mn2 = (const float*)d_in[8];
    const int* e1 = (const int*)d_in[9];
    const int* e2 = (const int*)d_in[10];
    const int* perm1 = (const int*)d_in[11];
    const int* perm2 = (const int*)d_in[12];
    const int* src1 = e1;       const int* dst1 = e1 + NE;
    const int* src2 = e2;       const int* dst2 = e2 + NE;
    float* out = (float*)d_out;

    // workspace carve
    char* w = (char*)d_ws;
    _Float16* xwi1 = (_Float16*)w; w += (size_t)NN * 256 * 2;  // 25.6 MB interleaved
    _Float16* xwi2 = (_Float16*)w; w += (size_t)NN * 256 * 2;
    int* cnt1 = (int*)w;  w += (size_t)NN * 4;
    int* cnt2 = (int*)w;  w += (size_t)NN * 4;
    int* cur1 = (int*)w;  w += (size_t)NN * 4;
    int* cur2 = (int*)w;  w += (size_t)NN * 4;
    int* rp1 = (int*)w;   w += (size_t)(NN + 4) * 4;
    int* rp2 = (int*)w;   w += (size_t)(NN + 4) * 4;
    int* col1 = (int*)w;  w += (size_t)NE * 4;
    int* col2 = (int*)w;  w += (size_t)NE * 4;
    float* dinv1 = (float*)w; w += (size_t)NN * 4;
    float* dinv2 = (float*)w; w += (size_t)NN * 4;
    int* part1 = (int*)w; w += (size_t)256 * 4;
    int* part2 = (int*)w; w += (size_t)256 * 4;

    float* s1 = out + 12800000L;
    float* s2 = out + 25600128L;
    const float* pos1 = out;
    const float* pos2 = out + 12800128L;

    k_init<<<dim3(256), 256, 0, stream>>>(cnt1, cnt2, s1, s2);
    k_count<<<dim3(1024), 256, 0, stream>>>(dst1, dst2, cnt1, cnt2);
    k_part<<<dim3(NB), 256, 0, stream>>>(cnt1, cnt2, part1, part2);
    k_scanp<<<dim3(1), 256, 0, stream>>>(part1, part2);
    k_apply<<<dim3(NB), 256, 0, stream>>>(cnt1, cnt2, part1, part2,
                                          rp1, rp2, cur1, cur2, dinv1, dinv2);
    k_fill_gemm<<<dim3(FILL_BLOCKS + GEMM_BLOCKS), 256, 0, stream>>>(
        src1, dst1, src2, dst2, cur1, cur2, col1, col2,
        x, W1, W2, mp1, mn1, mp2, mn2, perm1, perm2, dinv1, dinv2, xwi1, xwi2);
    k_agg<<<dim3(12500, 2), 256, 0, stream>>>(xwi1, xwi2,
                                              rp1, col1, dinv1, rp2, col2, dinv2,
                                              b1, b2, out);
    k_sum<<<dim3(128, 2), 256, 0, stream>>>(pos1, pos2, s1, s2);
}

// Round 7
// 533.220 us; speedup vs baseline: 1.8798x; 1.0383x over previous
//
#include <hip/hip_runtime.h>
#include <hip/hip_fp16.h>

#define NN 50000
#define NE 800000
#define D 128
#define NB 196        // ceil(50000/256)
#define FILL_BLOCKS 1024
#define GEMM_BLOCKS 3128   // 782 * 4
#define RNG 6250      // NN / 8 (dst range per XCD)
#define ESL 6250      // NE / 128 (edge slice per fill-rank)

typedef _Float16 half8_t __attribute__((ext_vector_type(8)));
typedef _Float16 half4_t __attribute__((ext_vector_type(4)));
typedef float f32x4 __attribute__((ext_vector_type(4)));

// ---------------- K0: init counters + summary slots ----------------
__global__ void k_init(int* cnt1, int* cnt2, float* s1, float* s2) {
    int i = blockIdx.x * blockDim.x + threadIdx.x;
    int stride = gridDim.x * blockDim.x;
    for (int j = i; j < NN; j += stride) { cnt1[j] = 0; cnt2[j] = 0; }
    if (i < D) { s1[i] = 0.f; s2[i] = 0.f; }
}

// ---------------- K1: in-degree histogram, XCD-binned ----------------
// blockIdx&7 selects a dst range (→ same XCD under round-robin dispatch), so
// all cnt atomics for a range stay in one XCD's L2 — no cross-XCD line ping-pong.
__global__ void k_count(const int* __restrict__ dst1, const int* __restrict__ dst2,
                        int* cnt1, int* cnt2) {
    int r = blockIdx.x & 7;
    int rank = blockIdx.x >> 3;          // 0..127
    unsigned lo = r * RNG;
    int base = rank * ESL;
    for (int e = base + threadIdx.x; e < base + ESL; e += 256) {
        int d1 = dst1[e];
        if ((unsigned)(d1 - lo) < RNG) atomicAdd(&cnt1[d1], 1);
        int d2 = dst2[e];
        if ((unsigned)(d2 - lo) < RNG) atomicAdd(&cnt2[d2], 1);
    }
}

// ---------------- K2a: per-block partial sums of counts (both graphs) ----------------
__global__ void k_part(const int* __restrict__ cnt1, const int* __restrict__ cnt2,
                       int* part1, int* part2) {
    __shared__ int sm1[256], sm2[256];
    int t = threadIdx.x;
    int idx = blockIdx.x * 256 + t;
    int v1 = (idx < NN) ? cnt1[idx] : 0;
    int v2 = (idx < NN) ? cnt2[idx] : 0;
    sm1[t] = v1; sm2[t] = v2;
    __syncthreads();
    for (int off = 128; off > 0; off >>= 1) {
        if (t < off) { sm1[t] += sm1[t + off]; sm2[t] += sm2[t + off]; }
        __syncthreads();
    }
    if (t == 0) { part1[blockIdx.x] = sm1[0]; part2[blockIdx.x] = sm2[0]; }
}

// ---------------- K2b: exclusive scan of block partials (one block) ----------------
__global__ void k_scanp(int* part1, int* part2) {
    __shared__ int sm1[256], sm2[256];
    int t = threadIdx.x;
    int v1 = (t < NB) ? part1[t] : 0;
    int v2 = (t < NB) ? part2[t] : 0;
    sm1[t] = v1; sm2[t] = v2;
    __syncthreads();
    for (int off = 1; off < 256; off <<= 1) {
        int a1 = (t >= off) ? sm1[t - off] : 0;
        int a2 = (t >= off) ? sm2[t - off] : 0;
        __syncthreads();
        sm1[t] += a1; sm2[t] += a2;
        __syncthreads();
    }
    if (t < NB) { part1[t] = sm1[t] - v1; part2[t] = sm2[t] - v2; }
}

// ---------------- K2c: apply block offsets -> rp, cur, dinv ----------------
__global__ void k_apply(const int* __restrict__ cnt1, const int* __restrict__ cnt2,
                        const int* __restrict__ part1, const int* __restrict__ part2,
                        int* rp1, int* rp2, int* cur1, int* cur2,
                        float* dinv1, float* dinv2) {
    __shared__ int sm1[256], sm2[256];
    int b = blockIdx.x, t = threadIdx.x;
    int idx = b * 256 + t;
    int v1 = (idx < NN) ? cnt1[idx] : 0;
    int v2 = (idx < NN) ? cnt2[idx] : 0;
    sm1[t] = v1; sm2[t] = v2;
    __syncthreads();
    for (int off = 1; off < 256; off <<= 1) {
        int a1 = (t >= off) ? sm1[t - off] : 0;
        int a2 = (t >= off) ? sm2[t - off] : 0;
        __syncthreads();
        sm1[t] += a1; sm2[t] += a2;
        __syncthreads();
    }
    int e1 = sm1[t] - v1 + part1[b];  // exclusive prefix
    int e2 = sm2[t] - v2 + part2[b];
    if (idx < NN) {
        rp1[idx] = e1; cur1[idx] = e1; dinv1[idx] = rsqrtf((float)(v1 + 1));
        rp2[idx] = e2; cur2[idx] = e2; dinv2[idx] = rsqrtf((float)(v2 + 1));
    } else if (idx == NN) {
        rp1[NN] = e1; rp2[NN] = e2;
    }
}

// ---------------- K3+K4 merged: XCD-binned CSR fill + 4 GEMMs ----------------
// Fill blocks (0..1023): blockIdx&7 = dst range → cur atomics and col writes are
// XCD-local (one L2 owns each line; single write-back). Gemm blocks overlap.
__launch_bounds__(256)
__global__ void k_fill_gemm(const int* __restrict__ src1, const int* __restrict__ dst1,
                            const int* __restrict__ src2, const int* __restrict__ dst2,
                            int* cur1, int* cur2, int* col1, int* col2,
                            const float* __restrict__ x,
                            const float* __restrict__ W1, const float* __restrict__ W2,
                            const float* __restrict__ mp1, const float* __restrict__ mn1,
                            const float* __restrict__ mp2, const float* __restrict__ mn2,
                            const int* __restrict__ perm1, const int* __restrict__ perm2,
                            const float* __restrict__ dinv1, const float* __restrict__ dinv2,
                            _Float16* xwi1, _Float16* xwi2) {
    __shared__ __align__(16) _Float16 WT[128][136];
    int t = threadIdx.x;

    if (blockIdx.x < FILL_BLOCKS) {
        int r = blockIdx.x & 7;
        int rank = blockIdx.x >> 3;       // 0..127
        unsigned lo = r * RNG;
        int base = rank * ESL;
        for (int e = base + t; e < base + ESL; e += 256) {
            int d1 = dst1[e];
            if ((unsigned)(d1 - lo) < RNG) {
                int p = atomicAdd(&cur1[d1], 1);
                col1[p] = src1[e];
            }
            int d2 = dst2[e];
            if ((unsigned)(d2 - lo) < RNG) {
                int p = atomicAdd(&cur2[d2], 1);
                col2[p] = src2[e];
            }
        }
        return;
    }

    // ---- GEMM part ----
    int g = blockIdx.x - FILL_BLOCKS;      // 0..3127
    int which = g / 782;                   // 0 = pos1, 1 = neg1, 2 = pos2, 3 = neg2
    int bx = g - which * 782;
    const float* W = (which < 2) ? W1 : W2;
    const float* mask = (which == 0) ? mp1 : (which == 1) ? mn1 : (which == 2) ? mp2 : mn2;
    const int* perm = (which == 1) ? perm1 : (which == 3) ? perm2 : nullptr;
    const float* dinv = (which < 2) ? dinv1 : dinv2;
    _Float16* out = ((which < 2) ? xwi1 : xwi2) + ((which & 1) ? 128 : 0);

    for (int i = 0; i < 16; i++) {
        int idx = i * 256 + t;
        int k = idx >> 5;
        int j4 = (idx & 31) * 4;
        float4 w = ((const float4*)W)[idx];
        WT[j4 + 0][k] = (_Float16)w.x;
        WT[j4 + 1][k] = (_Float16)w.y;
        WT[j4 + 2][k] = (_Float16)w.z;
        WT[j4 + 3][k] = (_Float16)w.w;
    }
    __syncthreads();

    int wave = t >> 6;
    int lane = t & 63;
    int quad = lane >> 4;
    int m = lane & 15;
    int tile = bx * 4 + wave;
    if (tile * 16 >= NN) return;

    int row = tile * 16 + m;
    int grow = perm ? perm[row] : row;
    const float* xrow = x + (long)grow * D;
    const float* mrow = mask + (long)grow * D;

    half8_t a[4];
    for (int kk = 0; kk < 4; kk++) {
        int k0 = kk * 32 + quad * 8;
        float4 xa = *(const float4*)(xrow + k0);
        float4 xb = *(const float4*)(xrow + k0 + 4);
        float4 ma = *(const float4*)(mrow + k0);
        float4 mb = *(const float4*)(mrow + k0 + 4);
        a[kk][0] = (_Float16)(xa.x * ma.x);
        a[kk][1] = (_Float16)(xa.y * ma.y);
        a[kk][2] = (_Float16)(xa.z * ma.z);
        a[kk][3] = (_Float16)(xa.w * ma.w);
        a[kk][4] = (_Float16)(xb.x * mb.x);
        a[kk][5] = (_Float16)(xb.y * mb.y);
        a[kk][6] = (_Float16)(xb.z * mb.z);
        a[kk][7] = (_Float16)(xb.w * mb.w);
    }

    int rbase = tile * 16 + quad * 4;
    float ds0 = dinv[rbase + 0], ds1 = dinv[rbase + 1];
    float ds2 = dinv[rbase + 2], ds3 = dinv[rbase + 3];

    for (int nt = 0; nt < 8; nt++) {
        f32x4 acc = {0.f, 0.f, 0.f, 0.f};
        for (int kk = 0; kk < 4; kk++) {
            half8_t b = *(const half8_t*)(&WT[nt * 16 + m][kk * 32 + quad * 8]);
            acc = __builtin_amdgcn_mfma_f32_16x16x32_f16(a[kk], b, acc, 0, 0, 0);
        }
        int n = nt * 16 + m;
        out[(long)(rbase + 0) * 256 + n] = (_Float16)(acc[0] * ds0);
        out[(long)(rbase + 1) * 256 + n] = (_Float16)(acc[1] * ds1);
        out[(long)(rbase + 2) * 256 + n] = (_Float16)(acc[2] * ds2);
        out[(long)(rbase + 3) * 256 + n] = (_Float16)(acc[3] * ds3);
    }
}

// ---------------- K5: CSR gather aggregation + bias + ReLU (no atomics) ----------------
__launch_bounds__(256)
__global__ void k_agg(const _Float16* __restrict__ xwi1, const _Float16* __restrict__ xwi2,
                      const int* __restrict__ rp1, const int* __restrict__ col1,
                      const float* __restrict__ dinv1,
                      const int* __restrict__ rp2, const int* __restrict__ col2,
                      const float* __restrict__ dinv2,
                      const float* __restrict__ b1, const float* __restrict__ b2,
                      float* out) {
    int g = blockIdx.y;
    const _Float16* xwi = g ? xwi2 : xwi1;
    const int* rp = g ? rp2 : rp1;
    const int* col = g ? col2 : col1;
    const float* dinv = g ? dinv2 : dinv1;
    const float* bias = g ? b2 : b1;
    float* pos_out = out + (g ? 12800128L : 0L);
    float* neg_out = out + (g ? 19200128L : 6400000L);

    int t = threadIdx.x;
    int wave = t >> 6, lane = t & 63;
    int i = blockIdx.x * 4 + wave;
    if (i >= NN) return;
    int j4 = lane * 4;

    half4_t sv = *(const half4_t*)(xwi + (long)i * 256 + j4);
    float a0 = (float)sv[0], a1 = (float)sv[1], a2 = (float)sv[2], a3 = (float)sv[3];
    int e0 = rp[i], e1 = rp[i + 1];
    int e = e0;
    for (; e + 8 <= e1; e += 8) {
        int s0 = col[e + 0], s1 = col[e + 1], s2 = col[e + 2], s3 = col[e + 3];
        int s4 = col[e + 4], s5 = col[e + 5], s6 = col[e + 6], s7 = col[e + 7];
        half4_t v0 = *(const half4_t*)(xwi + (long)s0 * 256 + j4);
        half4_t v1 = *(const half4_t*)(xwi + (long)s1 * 256 + j4);
        half4_t v2 = *(const half4_t*)(xwi + (long)s2 * 256 + j4);
        half4_t v3 = *(const half4_t*)(xwi + (long)s3 * 256 + j4);
        half4_t v4 = *(const half4_t*)(xwi + (long)s4 * 256 + j4);
        half4_t v5 = *(const half4_t*)(xwi + (long)s5 * 256 + j4);
        half4_t v6 = *(const half4_t*)(xwi + (long)s6 * 256 + j4);
        half4_t v7 = *(const half4_t*)(xwi + (long)s7 * 256 + j4);
        a0 += (float)v0[0] + (float)v1[0] + (float)v2[0] + (float)v3[0]
            + (float)v4[0] + (float)v5[0] + (float)v6[0] + (float)v7[0];
        a1 += (float)v0[1] + (float)v1[1] + (float)v2[1] + (float)v3[1]
            + (float)v4[1] + (float)v5[1] + (float)v6[1] + (float)v7[1];
        a2 += (float)v0[2] + (float)v1[2] + (float)v2[2] + (float)v3[2]
            + (float)v4[2] + (float)v5[2] + (float)v6[2] + (float)v7[2];
        a3 += (float)v0[3] + (float)v1[3] + (float)v2[3] + (float)v3[3]
            + (float)v4[3] + (float)v5[3] + (float)v6[3] + (float)v7[3];
    }
    for (; e + 4 <= e1; e += 4) {
        int s0 = col[e + 0], s1 = col[e + 1], s2 = col[e + 2], s3 = col[e + 3];
        half4_t v0 = *(const half4_t*)(xwi + (long)s0 * 256 + j4);
        half4_t v1 = *(const half4_t*)(xwi + (long)s1 * 256 + j4);
        half4_t v2 = *(const half4_t*)(xwi + (long)s2 * 256 + j4);
        half4_t v3 = *(const half4_t*)(xwi + (long)s3 * 256 + j4);
        a0 += (float)v0[0] + (float)v1[0] + (float)v2[0] + (float)v3[0];
        a1 += (float)v0[1] + (float)v1[1] + (float)v2[1] + (float)v3[1];
        a2 += (float)v0[2] + (float)v1[2] + (float)v2[2] + (float)v3[2];
        a3 += (float)v0[3] + (float)v1[3] + (float)v2[3] + (float)v3[3];
    }
    for (; e < e1; e++) {
        int s = col[e];
        half4_t v = *(const half4_t*)(xwi + (long)s * 256 + j4);
        a0 += (float)v[0]; a1 += (float)v[1]; a2 += (float)v[2]; a3 += (float)v[3];
    }
    float di = dinv[i];
    int jj = (lane < 32) ? j4 : (j4 - 128);
    const f32x4* bp = (const f32x4*)(bias + jj);
    f32x4 bv = *bp;
    f32x4 o;
    o[0] = fmaxf(0.f, di * a0 + bv[0]);
    o[1] = fmaxf(0.f, di * a1 + bv[1]);
    o[2] = fmaxf(0.f, di * a2 + bv[2]);
    o[3] = fmaxf(0.f, di * a3 + bv[3]);
    float* dst = ((lane < 32) ? pos_out : neg_out) + (long)i * D + jj;
    __builtin_nontemporal_store(o, (f32x4*)dst);
}

// ---------------- K6: summary mean over pos_h ----------------
__launch_bounds__(256)
__global__ void k_sum(const float* __restrict__ pos1, const float* __restrict__ pos2,
                      float* s1, float* s2) {
    int g = blockIdx.y;
    const float* pos = g ? pos2 : pos1;
    float* s = g ? s2 : s1;
    int t = threadIdx.x;
    int rg = t >> 5;
    int j = (t & 31) * 4;
    float4 acc = {0.f, 0.f, 0.f, 0.f};
    for (int i = blockIdx.x * 8 + rg; i < NN; i += gridDim.x * 8) {
        float4 v = *(const float4*)(pos + (long)i * D + j);
        acc.x += v.x; acc.y += v.y; acc.z += v.z; acc.w += v.w;
    }
    __shared__ float sm[8][128];
    sm[rg][j + 0] = acc.x;
    sm[rg][j + 1] = acc.y;
    sm[rg][j + 2] = acc.z;
    sm[rg][j + 3] = acc.w;
    __syncthreads();
    if (t < 128) {
        float v = 0.f;
        for (int r = 0; r < 8; r++) v += sm[r][t];
        atomicAdd(&s[t], v * (1.0f / NN));
    }
}

extern "C" void kernel_launch(void* const* d_in, const int* in_sizes, int n_in,
                              void* d_out, int out_size, void* d_ws, size_t ws_size,
                              hipStream_t stream) {
    const float* x   = (const float*)d_in[0];
    const float* W1  = (const float*)d_in[1];
    const float* b1  = (const float*)d_in[2];
    const float* W2  = (const float*)d_in[3];
    const float* b2  = (const float*)d_in[4];
    const float* mp1 = (const float*)d_in[5];
    const float* mn1 = (const float*)d_in[6];
    const float* mp2 = (const float*)d_in[7];
    const float* mn2 = (const float*)d_in[8];
    const int* e1 = (const int*)d_in[9];
    const int* e2 = (const int*)d_in[10];
    const int* perm1 = (const int*)d_in[11];
    const int* perm2 = (const int*)d_in[12];
    const int* src1 = e1;       const int* dst1 = e1 + NE;
    const int* src2 = e2;       const int* dst2 = e2 + NE;
    float* out = (float*)d_out;

    // workspace carve
    char* w = (char*)d_ws;
    _Float16* xwi1 = (_Float16*)w; w += (size_t)NN * 256 * 2;  // 25.6 MB interleaved
    _Float16* xwi2 = (_Float16*)w; w += (size_t)NN * 256 * 2;
    int* cnt1 = (int*)w;  w += (size_t)NN * 4;
    int* cnt2 = (int*)w;  w += (size_t)NN * 4;
    int* cur1 = (int*)w;  w += (size_t)NN * 4;
    int* cur2 = (int*)w;  w += (size_t)NN * 4;
    int* rp1 = (int*)w;   w += (size_t)(NN + 4) * 4;
    int* rp2 = (int*)w;   w += (size_t)(NN + 4) * 4;
    int* col1 = (int*)w;  w += (size_t)NE * 4;
    int* col2 = (int*)w;  w += (size_t)NE * 4;
    float* dinv1 = (float*)w; w += (size_t)NN * 4;
    float* dinv2 = (float*)w; w += (size_t)NN * 4;
    int* part1 = (int*)w; w += (size_t)256 * 4;
    int* part2 = (int*)w; w += (size_t)256 * 4;

    float* s1 = out + 12800000L;
    float* s2 = out + 25600128L;
    const float* pos1 = out;
    const float* pos2 = out + 12800128L;

    k_init<<<dim3(256), 256, 0, stream>>>(cnt1, cnt2, s1, s2);
    k_count<<<dim3(1024), 256, 0, stream>>>(dst1, dst2, cnt1, cnt2);
    k_part<<<dim3(NB), 256, 0, stream>>>(cnt1, cnt2, part1, part2);
    k_scanp<<<dim3(1), 256, 0, stream>>>(part1, part2);
    k_apply<<<dim3(NB), 256, 0, stream>>>(cnt1, cnt2, part1, part2,
                                          rp1, rp2, cur1, cur2, dinv1, dinv2);
    k_fill_gemm<<<dim3(FILL_BLOCKS + GEMM_BLOCKS), 256, 0, stream>>>(
        src1, dst1, src2, dst2, cur1, cur2, col1, col2,
        x, W1, W2, mp1, mn1, mp2, mn2, perm1, perm2, dinv1, dinv2, xwi1, xwi2);
    k_agg<<<dim3(12500, 2), 256, 0, stream>>>(xwi1, xwi2,
                                              rp1, col1, dinv1, rp2, col2, dinv2,
                                              b1, b2, out);
    k_sum<<<dim3(128, 2), 256, 0, stream>>>(pos1, pos2, s1, s2);
}